// Round 3
// baseline (13160.150 us; speedup 1.0000x reference)
//
#include <hip/hip_runtime.h>
#include <hip/hip_bf16.h>

// VQ-VAE encoder, round 3: outputs are FLOAT32 (256MiB d_out).
// d_out doubles as scratch: h1->half2, h2->half1, h3->half2, z->half1(=z_e),
// z_q->half2 (gather). ws holds only tails/scales/cnh/ids (<1MiB).

#define B_   32
#define T_   4096
#define E_   256
#define CIN_ 12
#define LM_  4096

// ---------------- conv1: (B,T,12) -> main (B,256,4096) + tail (B,256) ----------------
__global__ __launch_bounds__(256) void conv1_kernel(
    const float* __restrict__ x, const float* __restrict__ w1,
    const float* __restrict__ b1, float* __restrict__ out_main,
    float* __restrict__ out_tail) {
  __shared__ __align__(16) float xs[259][12];
  __shared__ __align__(16) float wsh[E_ * 48];
  __shared__ float bs[E_];
  const int tid = threadIdx.x;
  const int b = blockIdx.y;
  const int l0 = blockIdx.x * 256;
  for (int idx = tid; idx < 259 * 12; idx += 256) {
    int r = idx / 12, c = idx - r * 12;
    int t = l0 - 2 + r;
    xs[r][c] = (t >= 0 && t < T_) ? x[((size_t)b * T_ + t) * CIN_ + c] : 0.f;
  }
  for (int idx = tid; idx < E_ * 48; idx += 256) wsh[idx] = w1[idx];
  bs[tid] = b1[tid];
  __syncthreads();
  float xr[4][12];
  #pragma unroll
  for (int r = 0; r < 4; ++r)
    #pragma unroll
    for (int c = 0; c < 12; ++c) xr[r][c] = xs[tid + r][c];
  const int l = l0 + tid;
  for (int e = 0; e < E_; ++e) {
    float acc = bs[e];
    #pragma unroll
    for (int c = 0; c < 12; ++c) {
      const float4 wv = *(const float4*)&wsh[e * 48 + c * 4];
      acc += wv.x * xr[0][c] + wv.y * xr[1][c] + wv.z * xr[2][c] + wv.w * xr[3][c];
    }
    if (l < LM_)       out_main[((size_t)b * E_ + e) * LM_ + l] = acc;
    else if (l == LM_) out_tail[(size_t)b * E_ + e] = acc;
  }
}

// -------- BN train stats: scale=g*rsqrt(var+eps), shift=be-m*scale --------
__global__ __launch_bounds__(256) void bnstats_kernel(
    const float* __restrict__ hmain, const float* __restrict__ htail,
    const float* __restrict__ g, const float* __restrict__ be,
    float* __restrict__ scale, float* __restrict__ shift) {
  const int c = blockIdx.x, tid = threadIdx.x;
  const int Ltot = htail ? (LM_ + 1) : LM_;
  double s = 0.0, s2 = 0.0;
  for (int b = 0; b < B_; ++b) {
    const float* p = hmain + ((size_t)b * E_ + c) * LM_;
    for (int t = tid; t < Ltot; t += 256) {
      float v = (t < LM_) ? p[t] : htail[(size_t)b * E_ + c];
      s += v; s2 += (double)v * (double)v;
    }
  }
  __shared__ double sh[256], sh2[256];
  sh[tid] = s; sh2[tid] = s2; __syncthreads();
  for (int off = 128; off > 0; off >>= 1) {
    if (tid < off) { sh[tid] += sh[tid + off]; sh2[tid] += sh2[tid + off]; }
    __syncthreads();
  }
  if (tid == 0) {
    double N = (double)B_ * (double)Ltot;
    double m = sh[0] / N, var = sh2[0] / N - m * m;
    double a = (double)g[c] / sqrt(var + 1e-5);
    scale[c] = (float)a;
    shift[c] = (float)((double)be[c] - m * a);
  }
}

// -------- main conv (256->256, k=4); BN+ReLU folded into load. --------
// MODE 0: out (B,E,4096).  MODE 1: out (B,E,4097)=main+tail.  MODE 2: z (B,T,E).
template <int MODE>
__global__ __launch_bounds__(256) void conv_mid(
    const float* __restrict__ in_main, const float* __restrict__ in_tail,
    const float* __restrict__ w, const float* __restrict__ bias,
    const float* __restrict__ scale, const float* __restrict__ shift,
    float* __restrict__ out, float* __restrict__ out_tail, int pad) {
  __shared__ __align__(16) float in_sh[16][68];
  __shared__ __align__(16) float w_sh[16][64][4];   // [c][e ^ (c&7)][k]
  __shared__ float sc_sh[E_], sf_sh[E_];
  const int tid = threadIdx.x;
  const int tx = tid & 15, ty = tid >> 4;
  const int b = blockIdx.z;
  const int e0 = blockIdx.y * 64;
  const int l0 = blockIdx.x * 64;
  const float* inb = in_main + (size_t)b * E_ * LM_;
  const float* intb = in_tail ? (in_tail + (size_t)b * E_) : nullptr;
  sc_sh[tid] = scale[tid];
  sf_sh[tid] = shift[tid];
  float acc[4][4];
  #pragma unroll
  for (int i = 0; i < 4; ++i)
    #pragma unroll
    for (int j = 0; j < 4; ++j) acc[i][j] = 0.f;

  for (int cc = 0; cc < 16; ++cc) {
    __syncthreads();
    for (int idx = tid; idx < 16 * 68; idx += 256) {
      int r = idx / 68, u = idx - r * 68;
      int c = cc * 16 + r;
      int t = l0 - pad + u;
      float v = 0.f;                    // zero-pad is post-BN (pads the conv input)
      if (t >= 0) {
        float raw; bool ok = false;
        if (t < LM_)               { raw = inb[(size_t)c * LM_ + t]; ok = true; }
        else if (t == LM_ && intb) { raw = intb[c]; ok = true; }
        if (ok) v = fmaxf(fmaf(raw, sc_sh[c], sf_sh[c]), 0.f);
      }
      in_sh[r][u] = v;
    }
    for (int idx = tid; idx < 4096; idx += 256) {
      int e = idx >> 6, low = idx & 63;
      int c = low >> 2, k = low & 3;
      w_sh[c][e ^ (c & 7)][k] = w[(size_t)(e0 + e) * 1024 + cc * 64 + low];
    }
    __syncthreads();
    #pragma unroll
    for (int c = 0; c < 16; ++c) {
      const float4 xa = *(const float4*)&in_sh[c][tx * 4];
      const float4 xb = *(const float4*)&in_sh[c][tx * 4 + 4];
      const float xv[7] = {xa.x, xa.y, xa.z, xa.w, xb.x, xb.y, xb.z};
      #pragma unroll
      for (int i = 0; i < 4; ++i) {
        const float4 wv = *(const float4*)&w_sh[c][(ty * 4 + i) ^ (c & 7)][0];
        #pragma unroll
        for (int j = 0; j < 4; ++j)
          acc[i][j] += wv.x * xv[j] + wv.y * xv[j + 1] + wv.z * xv[j + 2] + wv.w * xv[j + 3];
      }
    }
  }

  float bi[4];
  #pragma unroll
  for (int i = 0; i < 4; ++i) bi[i] = bias[e0 + ty * 4 + i];

  if constexpr (MODE == 0) {
    float* ob = out + ((size_t)b * E_ + e0) * (size_t)LM_;
    const int lb = l0 + tx * 4;
    #pragma unroll
    for (int i = 0; i < 4; ++i) {
      float4 r = make_float4(acc[i][0] + bi[i], acc[i][1] + bi[i],
                             acc[i][2] + bi[i], acc[i][3] + bi[i]);
      *(float4*)&ob[(size_t)(ty * 4 + i) * LM_ + lb] = r;
    }
  } else if constexpr (MODE == 1) {
    const int lb = l0 + tx * 4;
    #pragma unroll
    for (int i = 0; i < 4; ++i) {
      const int e = e0 + ty * 4 + i;
      #pragma unroll
      for (int j = 0; j < 4; ++j) {
        const int l = lb + j;
        const float v = acc[i][j] + bi[i];
        if (l < LM_)       out[((size_t)b * E_ + e) * LM_ + l] = v;
        else if (l == LM_) out_tail[(size_t)b * E_ + e] = v;
      }
    }
  } else {
    const size_t base = ((size_t)b * T_ + l0) * E_ + e0 + ty * 4;
    #pragma unroll
    for (int j = 0; j < 4; ++j) {
      const int l = tx * 4 + j;
      float4 r = make_float4(acc[0][j] + bi[0], acc[1][j] + bi[1],
                             acc[2][j] + bi[2], acc[3][j] + bi[3]);
      *(float4*)&out[base + (size_t)l * E_] = r;
    }
  }
}

// -------- codebook half-norms: cnh[k] = 0.5*|c_k|^2 --------
__global__ __launch_bounds__(256) void cnorm_kernel(const float* __restrict__ cb,
                                                    float* __restrict__ cnh) {
  const int w = blockIdx.x * 4 + (threadIdx.x >> 6);
  const int lane = threadIdx.x & 63;
  const float4 v = *(const float4*)&cb[(size_t)w * E_ + lane * 4];
  float s = v.x * v.x + v.y * v.y + v.z * v.z + v.w * v.w;
  for (int off = 32; off > 0; off >>= 1) s += __shfl_xor(s, off, 64);
  if (lane == 0) cnh[w] = 0.5f * s;
}

// -------- fused VQ: argmax_k (z.c_k - 0.5|c_k|^2) == argmin_k d2 --------
__global__ __launch_bounds__(256) void vq_kernel(
    const float* __restrict__ z, const float* __restrict__ cb,
    const float* __restrict__ cnh, int* __restrict__ ids) {
  __shared__ __align__(16) float z_sh[64][64];
  __shared__ __align__(16) float c_sh[64][64];
  __shared__ float cn_sh[64];
  const int tid = threadIdx.x;
  const int tk = tid & 15, tt = tid >> 4;
  const int t0 = blockIdx.x * 64;
  float best[4]; int bidx[4];
  #pragma unroll
  for (int j = 0; j < 4; ++j) { best[j] = -3.4e38f; bidx[j] = 0; }

  for (int kt = 0; kt < 16; ++kt) {
    float acc[4][4];
    #pragma unroll
    for (int j = 0; j < 4; ++j)
      #pragma unroll
      for (int i = 0; i < 4; ++i) acc[j][i] = 0.f;
    for (int ec = 0; ec < 4; ++ec) {
      __syncthreads();
      for (int idx = tid; idx < 4096; idx += 256) {
        int rl = idx >> 6, e = idx & 63;
        int sw = ((((e >> 2) ^ (rl >> 2)) & 15) << 2) | (e & 3);
        z_sh[rl][sw] = z[((size_t)(t0 + rl)) * E_ + ec * 64 + e];
        c_sh[rl][sw] = cb[((size_t)(kt * 64 + rl)) * E_ + ec * 64 + e];
      }
      if (ec == 0 && tid < 64) cn_sh[tid] = cnh[kt * 64 + tid];
      __syncthreads();
      #pragma unroll
      for (int e4 = 0; e4 < 16; ++e4) {
        float4 zv[4], cv[4];
        #pragma unroll
        for (int j = 0; j < 4; ++j) zv[j] = *(const float4*)&z_sh[tt * 4 + j][((e4 ^ tt) & 15) << 2];
        #pragma unroll
        for (int i = 0; i < 4; ++i) cv[i] = *(const float4*)&c_sh[tk * 4 + i][((e4 ^ tk) & 15) << 2];
        #pragma unroll
        for (int j = 0; j < 4; ++j)
          #pragma unroll
          for (int i = 0; i < 4; ++i)
            acc[j][i] += zv[j].x * cv[i].x + zv[j].y * cv[i].y +
                         zv[j].z * cv[i].z + zv[j].w * cv[i].w;
      }
    }
    #pragma unroll
    for (int i = 0; i < 4; ++i) {
      const int k = kt * 64 + tk * 4 + i;
      const float cn = cn_sh[tk * 4 + i];
      #pragma unroll
      for (int j = 0; j < 4; ++j) {
        const float sco = acc[j][i] - cn;
        if (sco > best[j]) { best[j] = sco; bidx[j] = k; }
      }
    }
  }
  #pragma unroll
  for (int j = 0; j < 4; ++j) {
    for (int off = 8; off > 0; off >>= 1) {
      const float ov = __shfl_xor(best[j], off, 16);
      const int oi = __shfl_xor(bidx[j], off, 16);
      if (ov > best[j] || (ov == best[j] && oi < bidx[j])) { best[j] = ov; bidx[j] = oi; }
    }
  }
  if (tk == 0) {
    #pragma unroll
    for (int j = 0; j < 4; ++j) ids[t0 + tt * 4 + j] = bidx[j];
  }
}

// -------- gather z_q = codebook[ids] (f32) --------
__global__ __launch_bounds__(256) void gather_kernel(
    const int* __restrict__ ids, const float* __restrict__ cb,
    float* __restrict__ zq) {
  const int row = blockIdx.x * 4 + (threadIdx.x >> 6);
  const int lane = threadIdx.x & 63;
  const int id = ids[row];
  const float4 v = *(const float4*)&cb[(size_t)id * E_ + lane * 4];
  *(float4*)&zq[(size_t)row * E_ + lane * 4] = v;
}

extern "C" void kernel_launch(void* const* d_in, const int* in_sizes, int n_in,
                              void* d_out, int out_size, void* d_ws, size_t ws_size,
                              hipStream_t stream) {
  const float* x   = (const float*)d_in[0];
  const float* w1  = (const float*)d_in[1];
  const float* b1  = (const float*)d_in[2];
  const float* g1  = (const float*)d_in[3];
  const float* be1 = (const float*)d_in[4];
  const float* w2  = (const float*)d_in[5];
  const float* b2  = (const float*)d_in[6];
  const float* g2  = (const float*)d_in[7];
  const float* be2 = (const float*)d_in[8];
  const float* w3  = (const float*)d_in[9];
  const float* b3  = (const float*)d_in[10];
  const float* g3  = (const float*)d_in[11];
  const float* be3 = (const float*)d_in[12];
  const float* w4  = (const float*)d_in[13];
  const float* b4  = (const float*)d_in[14];
  const float* cb  = (const float*)d_in[15];

  char* ws = (char*)d_ws;
  float* tailA  = (float*)(ws);                 // (B,E) 32KB, reused h1/h3
  float* scale1 = (float*)(ws + 40960);  float* shift1 = (float*)(ws + 45056);
  float* scale2 = (float*)(ws + 49152);  float* shift2 = (float*)(ws + 53248);
  float* scale3 = (float*)(ws + 57344);  float* shift3 = (float*)(ws + 61440);
  float* cnh    = (float*)(ws + 65536);         // 4KB
  int*   ids    = (int*)(ws + 131072);          // 512KB

  float* half1 = (float*)d_out;                 // ends as z_e (B,T,E) f32
  float* half2 = half1 + (size_t)33554432;      // ends as z_q (B,T,E) f32

  cnorm_kernel<<<256, 256, 0, stream>>>(cb, cnh);
  // h1 -> half2 (+tail)
  conv1_kernel<<<dim3(17, 32), 256, 0, stream>>>(x, w1, b1, half2, tailA);
  bnstats_kernel<<<256, 256, 0, stream>>>(half2, tailA, g1, be1, scale1, shift1);
  // h2 -> half1
  conv_mid<0><<<dim3(64, 4, 32), 256, 0, stream>>>(half2, tailA, w2, b2, scale1, shift1,
                                                   half1, nullptr, 1);
  bnstats_kernel<<<256, 256, 0, stream>>>(half1, nullptr, g2, be2, scale2, shift2);
  // h3 -> half2 (+tail), h1 dead
  conv_mid<1><<<dim3(65, 4, 32), 256, 0, stream>>>(half1, nullptr, w3, b3, scale2, shift2,
                                                   half2, tailA, 2);
  bnstats_kernel<<<256, 256, 0, stream>>>(half2, tailA, g3, be3, scale3, shift3);
  // z -> half1 (final z_e), h2 dead
  conv_mid<2><<<dim3(64, 4, 32), 256, 0, stream>>>(half2, tailA, w4, b4, scale3, shift3,
                                                   half1, nullptr, 1);
  vq_kernel<<<2048, 256, 0, stream>>>(half1, cb, cnh, ids);
  // z_q -> half2 (final), h3 dead
  gather_kernel<<<32768, 256, 0, stream>>>(ids, cb, half2);
}

// Round 8
// 6581.400 us; speedup vs baseline: 1.9996x; 1.9996x over previous
//
#include <hip/hip_runtime.h>
#include <hip/hip_bf16.h>

// VQ-VAE encoder, round 8: r3-PROVEN pipeline (layout (B,E,L), same BN, same
// vq/gather), with conv_mid rebuilt as a 128x128 block tile / 8x8 register
// tile fp32 kernel (VALU-bound instead of LDS-bound). No MFMA (the r4-r7 MFMA
// structure fails with an unexplained constant error; parked).

#define B_   32
#define T_   4096
#define E_   256
#define CIN_ 12
#define LM_  4096
#define CCH  8

typedef __attribute__((ext_vector_type(4))) float f32x4;

// ---------------- conv1: (B,T,12) -> main (B,256,4096) + tail (B,256) ----------------
__global__ __launch_bounds__(256) void conv1_kernel(
    const float* __restrict__ x, const float* __restrict__ w1,
    const float* __restrict__ b1, float* __restrict__ out_main,
    float* __restrict__ out_tail) {
  __shared__ __align__(16) float xs[259][12];
  __shared__ __align__(16) float wsh[E_ * 48];
  __shared__ float bs[E_];
  const int tid = threadIdx.x;
  const int b = blockIdx.y;
  const int l0 = blockIdx.x * 256;
  for (int idx = tid; idx < 259 * 12; idx += 256) {
    int r = idx / 12, c = idx - r * 12;
    int t = l0 - 2 + r;
    xs[r][c] = (t >= 0 && t < T_) ? x[((size_t)b * T_ + t) * CIN_ + c] : 0.f;
  }
  for (int idx = tid; idx < E_ * 48; idx += 256) wsh[idx] = w1[idx];
  bs[tid] = b1[tid];
  __syncthreads();
  float xr[4][12];
  #pragma unroll
  for (int r = 0; r < 4; ++r)
    #pragma unroll
    for (int c = 0; c < 12; ++c) xr[r][c] = xs[tid + r][c];
  const int l = l0 + tid;
  for (int e = 0; e < E_; ++e) {
    float acc = bs[e];
    #pragma unroll
    for (int c = 0; c < 12; ++c) {
      const float4 wv = *(const float4*)&wsh[e * 48 + c * 4];
      acc += wv.x * xr[0][c] + wv.y * xr[1][c] + wv.z * xr[2][c] + wv.w * xr[3][c];
    }
    if (l < LM_)       out_main[((size_t)b * E_ + e) * LM_ + l] = acc;
    else if (l == LM_) out_tail[(size_t)b * E_ + e] = acc;
  }
}

// -------- BN train stats (r3 verbatim) --------
__global__ __launch_bounds__(256) void bnstats_kernel(
    const float* __restrict__ hmain, const float* __restrict__ htail,
    const float* __restrict__ g, const float* __restrict__ be,
    float* __restrict__ scale, float* __restrict__ shift) {
  const int c = blockIdx.x, tid = threadIdx.x;
  const int Ltot = htail ? (LM_ + 1) : LM_;
  double s = 0.0, s2 = 0.0;
  for (int b = 0; b < B_; ++b) {
    const float* p = hmain + ((size_t)b * E_ + c) * LM_;
    for (int t = tid; t < Ltot; t += 256) {
      float v = (t < LM_) ? p[t] : htail[(size_t)b * E_ + c];
      s += v; s2 += (double)v * (double)v;
    }
  }
  __shared__ double sh[256], sh2[256];
  sh[tid] = s; sh2[tid] = s2; __syncthreads();
  for (int off = 128; off > 0; off >>= 1) {
    if (tid < off) { sh[tid] += sh[tid + off]; sh2[tid] += sh2[tid + off]; }
    __syncthreads();
  }
  if (tid == 0) {
    double N = (double)B_ * (double)Ltot;
    double m = sh[0] / N, var = sh2[0] / N - m * m;
    double a = (double)g[c] / sqrt(var + 1e-5);
    scale[c] = (float)a;
    shift[c] = (float)((double)be[c] - m * a);
  }
}

// -------- conv 256->256 k=4, fp32, 128x128 block / 8x8 reg tile --------
// MODE 0: out (B,E,4096). MODE 1: main+tail (Lout 4097). MODE 2: z (B,T,E).
template <int MODE>
__global__ __launch_bounds__(256) void conv_mid(
    const float* __restrict__ in_main, const float* __restrict__ in_tail,
    const float* __restrict__ w, const float* __restrict__ bias,
    const float* __restrict__ scale, const float* __restrict__ shift,
    float* __restrict__ out, float* __restrict__ out_tail, int pad) {
  __shared__ __align__(16) float in_sh[CCH][132];     // cols: l0-pad+u, u 0..130
  __shared__ __align__(16) float w_sh[CCH][128][4];   // [c][e][k]
  __shared__ float sc_sh[E_], sf_sh[E_];
  const int tid = threadIdx.x;
  const int tx = tid & 15;           // l-cols: l0 + tx*8 + j (j 0..7)
  const int ty = tid >> 4;           // e-rows: e0 + ty + 16*i (i 0..7)
  const int b  = blockIdx.z;
  const int e0 = blockIdx.y * 128;
  const int l0 = blockIdx.x * 128;
  const float* inb = in_main + (size_t)b * E_ * LM_;
  const float* intb = in_tail ? (in_tail + (size_t)b * E_) : nullptr;
  sc_sh[tid] = scale[tid];
  sf_sh[tid] = shift[tid];

  float acc[8][8];
  #pragma unroll
  for (int i = 0; i < 8; ++i)
    #pragma unroll
    for (int j = 0; j < 8; ++j) acc[i][j] = 0.f;

  for (int cc = 0; cc < 32; ++cc) {
    __syncthreads();                  // prior chunk's reads done
    // ---- stage X: 8 rows x 131 normalized cols (f32x4 fast path) ----
    for (int idx = tid; idx < 264; idx += 256) {
      const int r = idx / 33, g = idx - r * 33;
      const int c = cc * CCH + r;
      const int u0 = g * 4;
      const int lbase = l0 - pad + u0;
      const float sc = sc_sh[c], sf = sf_sh[c];
      float ov[4];
      if (lbase >= 0 && lbase + 3 < LM_) {
        f32x4 v = *(const f32x4*)(inb + (size_t)c * LM_ + lbase);
        #pragma unroll
        for (int s = 0; s < 4; ++s) ov[s] = fmaxf(fmaf(v[s], sc, sf), 0.f);
      } else {
        #pragma unroll
        for (int s = 0; s < 4; ++s) {
          const int l = lbase + s;
          float o = 0.f;               // zero-pad is post-BN (pads conv input)
          if (l >= 0 && l < LM_)      o = fmaxf(fmaf(inb[(size_t)c * LM_ + l], sc, sf), 0.f);
          else if (l == LM_ && intb)  o = fmaxf(fmaf(intb[c], sc, sf), 0.f);
          ov[s] = o;
        }
      }
      f32x4 wv_ = {ov[0], ov[1], ov[2], ov[3]};
      *(f32x4*)&in_sh[r][u0] = wv_;
    }
    // ---- stage W: 8c x 128e x (4k) ----
    for (int idx = tid; idx < 1024; idx += 256) {
      const int c = idx >> 7, e = idx & 127;
      *(f32x4*)&w_sh[c][e][0] =
          *(const f32x4*)&w[(size_t)(e0 + e) * 1024 + (size_t)(cc * CCH + c) * 4];
    }
    __syncthreads();
    // ---- compute: per channel, 8x8x4 FMAs vs 11 b128 LDS reads ----
    for (int c = 0; c < CCH; ++c) {
      const f32x4 xa = *(const f32x4*)&in_sh[c][tx * 8];
      const f32x4 xb = *(const f32x4*)&in_sh[c][tx * 8 + 4];
      const f32x4 xc = *(const f32x4*)&in_sh[c][tx * 8 + 8];
      const float xv[11] = {xa.x, xa.y, xa.z, xa.w, xb.x, xb.y, xb.z, xb.w,
                            xc.x, xc.y, xc.z};
      #pragma unroll
      for (int i = 0; i < 8; ++i) {
        const f32x4 wv = *(const f32x4*)&w_sh[c][ty + 16 * i][0];
        #pragma unroll
        for (int j = 0; j < 8; ++j)
          acc[i][j] += wv.x * xv[j] + wv.y * xv[j + 1] + wv.z * xv[j + 2] + wv.w * xv[j + 3];
      }
    }
  }

  float bi[8];
  #pragma unroll
  for (int i = 0; i < 8; ++i) bi[i] = bias[e0 + ty + 16 * i];

  if constexpr (MODE == 0) {
    const int lb = l0 + tx * 8;
    #pragma unroll
    for (int i = 0; i < 8; ++i) {
      float* ob = out + ((size_t)b * E_ + e0 + ty + 16 * i) * (size_t)LM_ + lb;
      float4 r0 = make_float4(acc[i][0] + bi[i], acc[i][1] + bi[i],
                              acc[i][2] + bi[i], acc[i][3] + bi[i]);
      float4 r1 = make_float4(acc[i][4] + bi[i], acc[i][5] + bi[i],
                              acc[i][6] + bi[i], acc[i][7] + bi[i]);
      *(float4*)ob = r0;
      *(float4*)(ob + 4) = r1;
    }
  } else if constexpr (MODE == 1) {
    #pragma unroll
    for (int i = 0; i < 8; ++i) {
      const int e = e0 + ty + 16 * i;
      #pragma unroll
      for (int j = 0; j < 8; ++j) {
        const int col = l0 + tx * 8 + j;
        const float v = acc[i][j] + bi[i];
        if (col < LM_)       out[((size_t)b * E_ + e) * LM_ + col] = v;
        else if (col == LM_) out_tail[(size_t)b * E_ + e] = v;
      }
    }
  } else {
    #pragma unroll
    for (int j = 0; j < 8; ++j) {
      const int l = l0 + tx * 8 + j;
      float* zb = out + ((size_t)b * T_ + l) * E_ + e0 + ty;
      #pragma unroll
      for (int i = 0; i < 8; ++i) zb[16 * i] = acc[i][j] + bi[i];
    }
  }
}

// -------- codebook half-norms (r3 verbatim) --------
__global__ __launch_bounds__(256) void cnorm_kernel(const float* __restrict__ cb,
                                                    float* __restrict__ cnh) {
  const int w = blockIdx.x * 4 + (threadIdx.x >> 6);
  const int lane = threadIdx.x & 63;
  const float4 v = *(const float4*)&cb[(size_t)w * E_ + lane * 4];
  float s = v.x * v.x + v.y * v.y + v.z * v.z + v.w * v.w;
  for (int off = 32; off > 0; off >>= 1) s += __shfl_xor(s, off, 64);
  if (lane == 0) cnh[w] = 0.5f * s;
}

// -------- fused VQ argmin (r3 verbatim) --------
__global__ __launch_bounds__(256) void vq_kernel(
    const float* __restrict__ z, const float* __restrict__ cb,
    const float* __restrict__ cnh, int* __restrict__ ids) {
  __shared__ __align__(16) float z_sh[64][64];
  __shared__ __align__(16) float c_sh[64][64];
  __shared__ float cn_sh[64];
  const int tid = threadIdx.x;
  const int tk = tid & 15, tt = tid >> 4;
  const int t0 = blockIdx.x * 64;
  float best[4]; int bidx[4];
  #pragma unroll
  for (int j = 0; j < 4; ++j) { best[j] = -3.4e38f; bidx[j] = 0; }

  for (int kt = 0; kt < 16; ++kt) {
    float acc[4][4];
    #pragma unroll
    for (int j = 0; j < 4; ++j)
      #pragma unroll
      for (int i = 0; i < 4; ++i) acc[j][i] = 0.f;
    for (int ec = 0; ec < 4; ++ec) {
      __syncthreads();
      for (int idx = tid; idx < 4096; idx += 256) {
        int rl = idx >> 6, e = idx & 63;
        int sw = ((((e >> 2) ^ (rl >> 2)) & 15) << 2) | (e & 3);
        z_sh[rl][sw] = z[((size_t)(t0 + rl)) * E_ + ec * 64 + e];
        c_sh[rl][sw] = cb[((size_t)(kt * 64 + rl)) * E_ + ec * 64 + e];
      }
      if (ec == 0 && tid < 64) cn_sh[tid] = cnh[kt * 64 + tid];
      __syncthreads();
      #pragma unroll
      for (int e4 = 0; e4 < 16; ++e4) {
        float4 zv[4], cv[4];
        #pragma unroll
        for (int j = 0; j < 4; ++j) zv[j] = *(const float4*)&z_sh[tt * 4 + j][((e4 ^ tt) & 15) << 2];
        #pragma unroll
        for (int i = 0; i < 4; ++i) cv[i] = *(const float4*)&c_sh[tk * 4 + i][((e4 ^ tk) & 15) << 2];
        #pragma unroll
        for (int j = 0; j < 4; ++j)
          #pragma unroll
          for (int i = 0; i < 4; ++i)
            acc[j][i] += zv[j].x * cv[i].x + zv[j].y * cv[i].y +
                         zv[j].z * cv[i].z + zv[j].w * cv[i].w;
      }
    }
    #pragma unroll
    for (int i = 0; i < 4; ++i) {
      const int k = kt * 64 + tk * 4 + i;
      const float cn = cn_sh[tk * 4 + i];
      #pragma unroll
      for (int j = 0; j < 4; ++j) {
        const float sco = acc[j][i] - cn;
        if (sco > best[j]) { best[j] = sco; bidx[j] = k; }
      }
    }
  }
  #pragma unroll
  for (int j = 0; j < 4; ++j) {
    for (int off = 8; off > 0; off >>= 1) {
      const float ov = __shfl_xor(best[j], off, 16);
      const int oi = __shfl_xor(bidx[j], off, 16);
      if (ov > best[j] || (ov == best[j] && oi < bidx[j])) { best[j] = ov; bidx[j] = oi; }
    }
  }
  if (tk == 0) {
    #pragma unroll
    for (int j = 0; j < 4; ++j) ids[t0 + tt * 4 + j] = bidx[j];
  }
}

// -------- gather z_q = codebook[ids] (r3 verbatim) --------
__global__ __launch_bounds__(256) void gather_kernel(
    const int* __restrict__ ids, const float* __restrict__ cb,
    float* __restrict__ zq) {
  const int row = blockIdx.x * 4 + (threadIdx.x >> 6);
  const int lane = threadIdx.x & 63;
  const int id = ids[row];
  const float4 v = *(const float4*)&cb[(size_t)id * E_ + lane * 4];
  *(float4*)&zq[(size_t)row * E_ + lane * 4] = v;
}

extern "C" void kernel_launch(void* const* d_in, const int* in_sizes, int n_in,
                              void* d_out, int out_size, void* d_ws, size_t ws_size,
                              hipStream_t stream) {
  const float* x   = (const float*)d_in[0];
  const float* w1  = (const float*)d_in[1];
  const float* b1  = (const float*)d_in[2];
  const float* g1  = (const float*)d_in[3];
  const float* be1 = (const float*)d_in[4];
  const float* w2  = (const float*)d_in[5];
  const float* b2  = (const float*)d_in[6];
  const float* g2  = (const float*)d_in[7];
  const float* be2 = (const float*)d_in[8];
  const float* w3  = (const float*)d_in[9];
  const float* b3  = (const float*)d_in[10];
  const float* g3  = (const float*)d_in[11];
  const float* be3 = (const float*)d_in[12];
  const float* w4  = (const float*)d_in[13];
  const float* b4  = (const float*)d_in[14];
  const float* cb  = (const float*)d_in[15];

  // r3-proven ws map: all usage < 655360 bytes.
  char* ws = (char*)d_ws;
  float* tailA  = (float*)(ws);                 // (B,E) 32KB, reused h1/h3
  float* scale1 = (float*)(ws + 40960);  float* shift1 = (float*)(ws + 45056);
  float* scale2 = (float*)(ws + 49152);  float* shift2 = (float*)(ws + 53248);
  float* scale3 = (float*)(ws + 57344);  float* shift3 = (float*)(ws + 61440);
  float* cnh    = (float*)(ws + 65536);         // 4KB
  int*   ids    = (int*)(ws + 131072);          // 512KB

  float* half1 = (float*)d_out;                 // ends as z_e (B,T,E) f32
  float* half2 = half1 + (size_t)33554432;      // ends as z_q (B,T,E) f32

  cnorm_kernel<<<256, 256, 0, stream>>>(cb, cnh);
  // h1 -> half2 (+tail)
  conv1_kernel<<<dim3(17, 32), 256, 0, stream>>>(x, w1, b1, half2, tailA);
  bnstats_kernel<<<256, 256, 0, stream>>>(half2, tailA, g1, be1, scale1, shift1);
  // h2 -> half1
  conv_mid<0><<<dim3(32, 2, 32), 256, 0, stream>>>(half2, tailA, w2, b2, scale1, shift1,
                                                   half1, nullptr, 1);
  bnstats_kernel<<<256, 256, 0, stream>>>(half1, nullptr, g2, be2, scale2, shift2);
  // h3 -> half2 (+tail), h1 dead
  conv_mid<1><<<dim3(33, 2, 32), 256, 0, stream>>>(half1, nullptr, w3, b3, scale2, shift2,
                                                   half2, tailA, 2);
  bnstats_kernel<<<256, 256, 0, stream>>>(half2, tailA, g3, be3, scale3, shift3);
  // z -> half1 (final z_e), h2 dead
  conv_mid<2><<<dim3(32, 2, 32), 256, 0, stream>>>(half2, tailA, w4, b4, scale3, shift3,
                                                   half1, nullptr, 1);
  vq_kernel<<<2048, 256, 0, stream>>>(half1, cb, cnh, ids);
  // z_q -> half2 (final), h3 dead
  gather_kernel<<<32768, 256, 0, stream>>>(ids, cb, half2);
}

// Round 9
// 3891.448 us; speedup vs baseline: 3.3818x; 1.6912x over previous
//
#include <hip/hip_runtime.h>
#include <hip/hip_bf16.h>

// VQ-VAE encoder, round 9: r8 pipeline (proven) + MFMA VQ.
// vq: scores = z.cT - 0.5|c|^2 via mfma_f32_16x16x32_bf16, 2-way hi/lo split
// (hh+hl+lh). Codebook pre-split to bf16 planes stored in half2 (dead between
// conv4 and gather). z rows held in registers as B-fragments (32 rows/wave).

#define B_   32
#define T_   4096
#define E_   256
#define CIN_ 12
#define LM_  4096
#define CCH  8

typedef __attribute__((ext_vector_type(4))) float f32x4;
typedef __attribute__((ext_vector_type(8))) short bf16x8;
typedef __attribute__((ext_vector_type(8))) unsigned short u16x8;

__device__ __forceinline__ unsigned int bf_rne(float v) {
  unsigned int u = __float_as_uint(v);
  return (u + 0x7fffu + ((u >> 16) & 1u)) >> 16;
}
__device__ __forceinline__ void split2(float v, unsigned short& h, unsigned short& l) {
  unsigned int hu = bf_rne(v);
  h = (unsigned short)hu;
  l = (unsigned short)bf_rne(v - __uint_as_float(hu << 16));
}

// ---------------- conv1 (r8 verbatim) ----------------
__global__ __launch_bounds__(256) void conv1_kernel(
    const float* __restrict__ x, const float* __restrict__ w1,
    const float* __restrict__ b1, float* __restrict__ out_main,
    float* __restrict__ out_tail) {
  __shared__ __align__(16) float xs[259][12];
  __shared__ __align__(16) float wsh[E_ * 48];
  __shared__ float bs[E_];
  const int tid = threadIdx.x;
  const int b = blockIdx.y;
  const int l0 = blockIdx.x * 256;
  for (int idx = tid; idx < 259 * 12; idx += 256) {
    int r = idx / 12, c = idx - r * 12;
    int t = l0 - 2 + r;
    xs[r][c] = (t >= 0 && t < T_) ? x[((size_t)b * T_ + t) * CIN_ + c] : 0.f;
  }
  for (int idx = tid; idx < E_ * 48; idx += 256) wsh[idx] = w1[idx];
  bs[tid] = b1[tid];
  __syncthreads();
  float xr[4][12];
  #pragma unroll
  for (int r = 0; r < 4; ++r)
    #pragma unroll
    for (int c = 0; c < 12; ++c) xr[r][c] = xs[tid + r][c];
  const int l = l0 + tid;
  for (int e = 0; e < E_; ++e) {
    float acc = bs[e];
    #pragma unroll
    for (int c = 0; c < 12; ++c) {
      const float4 wv = *(const float4*)&wsh[e * 48 + c * 4];
      acc += wv.x * xr[0][c] + wv.y * xr[1][c] + wv.z * xr[2][c] + wv.w * xr[3][c];
    }
    if (l < LM_)       out_main[((size_t)b * E_ + e) * LM_ + l] = acc;
    else if (l == LM_) out_tail[(size_t)b * E_ + e] = acc;
  }
}

// -------- BN train stats (r8 verbatim) --------
__global__ __launch_bounds__(256) void bnstats_kernel(
    const float* __restrict__ hmain, const float* __restrict__ htail,
    const float* __restrict__ g, const float* __restrict__ be,
    float* __restrict__ scale, float* __restrict__ shift) {
  const int c = blockIdx.x, tid = threadIdx.x;
  const int Ltot = htail ? (LM_ + 1) : LM_;
  double s = 0.0, s2 = 0.0;
  for (int b = 0; b < B_; ++b) {
    const float* p = hmain + ((size_t)b * E_ + c) * LM_;
    for (int t = tid; t < Ltot; t += 256) {
      float v = (t < LM_) ? p[t] : htail[(size_t)b * E_ + c];
      s += v; s2 += (double)v * (double)v;
    }
  }
  __shared__ double sh[256], sh2[256];
  sh[tid] = s; sh2[tid] = s2; __syncthreads();
  for (int off = 128; off > 0; off >>= 1) {
    if (tid < off) { sh[tid] += sh[tid + off]; sh2[tid] += sh2[tid + off]; }
    __syncthreads();
  }
  if (tid == 0) {
    double N = (double)B_ * (double)Ltot;
    double m = sh[0] / N, var = sh2[0] / N - m * m;
    double a = (double)g[c] / sqrt(var + 1e-5);
    scale[c] = (float)a;
    shift[c] = (float)((double)be[c] - m * a);
  }
}

// -------- conv 256->256 k=4, fp32, 128x128 block / 8x8 reg tile (r8 verbatim) --------
template <int MODE>
__global__ __launch_bounds__(256) void conv_mid(
    const float* __restrict__ in_main, const float* __restrict__ in_tail,
    const float* __restrict__ w, const float* __restrict__ bias,
    const float* __restrict__ scale, const float* __restrict__ shift,
    float* __restrict__ out, float* __restrict__ out_tail, int pad) {
  __shared__ __align__(16) float in_sh[CCH][132];
  __shared__ __align__(16) float w_sh[CCH][128][4];
  __shared__ float sc_sh[E_], sf_sh[E_];
  const int tid = threadIdx.x;
  const int tx = tid & 15;
  const int ty = tid >> 4;
  const int b  = blockIdx.z;
  const int e0 = blockIdx.y * 128;
  const int l0 = blockIdx.x * 128;
  const float* inb = in_main + (size_t)b * E_ * LM_;
  const float* intb = in_tail ? (in_tail + (size_t)b * E_) : nullptr;
  sc_sh[tid] = scale[tid];
  sf_sh[tid] = shift[tid];

  float acc[8][8];
  #pragma unroll
  for (int i = 0; i < 8; ++i)
    #pragma unroll
    for (int j = 0; j < 8; ++j) acc[i][j] = 0.f;

  for (int cc = 0; cc < 32; ++cc) {
    __syncthreads();
    for (int idx = tid; idx < 264; idx += 256) {
      const int r = idx / 33, g = idx - r * 33;
      const int c = cc * CCH + r;
      const int u0 = g * 4;
      const int lbase = l0 - pad + u0;
      const float sc = sc_sh[c], sf = sf_sh[c];
      float ov[4];
      if (lbase >= 0 && lbase + 3 < LM_) {
        f32x4 v = *(const f32x4*)(inb + (size_t)c * LM_ + lbase);
        #pragma unroll
        for (int s = 0; s < 4; ++s) ov[s] = fmaxf(fmaf(v[s], sc, sf), 0.f);
      } else {
        #pragma unroll
        for (int s = 0; s < 4; ++s) {
          const int l = lbase + s;
          float o = 0.f;
          if (l >= 0 && l < LM_)      o = fmaxf(fmaf(inb[(size_t)c * LM_ + l], sc, sf), 0.f);
          else if (l == LM_ && intb)  o = fmaxf(fmaf(intb[c], sc, sf), 0.f);
          ov[s] = o;
        }
      }
      f32x4 wv_ = {ov[0], ov[1], ov[2], ov[3]};
      *(f32x4*)&in_sh[r][u0] = wv_;
    }
    for (int idx = tid; idx < 1024; idx += 256) {
      const int c = idx >> 7, e = idx & 127;
      *(f32x4*)&w_sh[c][e][0] =
          *(const f32x4*)&w[(size_t)(e0 + e) * 1024 + (size_t)(cc * CCH + c) * 4];
    }
    __syncthreads();
    for (int c = 0; c < CCH; ++c) {
      const f32x4 xa = *(const f32x4*)&in_sh[c][tx * 8];
      const f32x4 xb = *(const f32x4*)&in_sh[c][tx * 8 + 4];
      const f32x4 xc = *(const f32x4*)&in_sh[c][tx * 8 + 8];
      const float xv[11] = {xa.x, xa.y, xa.z, xa.w, xb.x, xb.y, xb.z, xb.w,
                            xc.x, xc.y, xc.z};
      #pragma unroll
      for (int i = 0; i < 8; ++i) {
        const f32x4 wv = *(const f32x4*)&w_sh[c][ty + 16 * i][0];
        #pragma unroll
        for (int j = 0; j < 8; ++j)
          acc[i][j] += wv.x * xv[j] + wv.y * xv[j + 1] + wv.z * xv[j + 2] + wv.w * xv[j + 3];
      }
    }
  }

  float bi[8];
  #pragma unroll
  for (int i = 0; i < 8; ++i) bi[i] = bias[e0 + ty + 16 * i];

  if constexpr (MODE == 0) {
    const int lb = l0 + tx * 8;
    #pragma unroll
    for (int i = 0; i < 8; ++i) {
      float* ob = out + ((size_t)b * E_ + e0 + ty + 16 * i) * (size_t)LM_ + lb;
      float4 r0 = make_float4(acc[i][0] + bi[i], acc[i][1] + bi[i],
                              acc[i][2] + bi[i], acc[i][3] + bi[i]);
      float4 r1 = make_float4(acc[i][4] + bi[i], acc[i][5] + bi[i],
                              acc[i][6] + bi[i], acc[i][7] + bi[i]);
      *(float4*)ob = r0;
      *(float4*)(ob + 4) = r1;
    }
  } else if constexpr (MODE == 1) {
    #pragma unroll
    for (int i = 0; i < 8; ++i) {
      const int e = e0 + ty + 16 * i;
      #pragma unroll
      for (int j = 0; j < 8; ++j) {
        const int col = l0 + tx * 8 + j;
        const float v = acc[i][j] + bi[i];
        if (col < LM_)       out[((size_t)b * E_ + e) * LM_ + col] = v;
        else if (col == LM_) out_tail[(size_t)b * E_ + e] = v;
      }
    }
  } else {
    #pragma unroll
    for (int j = 0; j < 8; ++j) {
      const int l = l0 + tx * 8 + j;
      float* zb = out + ((size_t)b * T_ + l) * E_ + e0 + ty;
      #pragma unroll
      for (int i = 0; i < 8; ++i) zb[16 * i] = acc[i][j] + bi[i];
    }
  }
}

// -------- cbprep: split codebook -> bf16 hi/lo planes + half-norms --------
__global__ __launch_bounds__(256) void cbprep_kernel(
    const float* __restrict__ cb, unsigned short* __restrict__ cbh,
    unsigned short* __restrict__ cbl, float* __restrict__ cnh) {
  const int code = blockIdx.x * 4 + (threadIdx.x >> 6);
  const int lane = threadIdx.x & 63;
  const f32x4 v = *(const f32x4*)&cb[(size_t)code * E_ + lane * 4];
  ushort4 h, l;
  split2(v.x, h.x, l.x); split2(v.y, h.y, l.y);
  split2(v.z, h.z, l.z); split2(v.w, h.w, l.w);
  *(ushort4*)&cbh[(size_t)code * E_ + lane * 4] = h;
  *(ushort4*)&cbl[(size_t)code * E_ + lane * 4] = l;
  float s = v.x * v.x + v.y * v.y + v.z * v.z + v.w * v.w;
  for (int off = 32; off > 0; off >>= 1) s += __shfl_xor(s, off, 64);
  if (lane == 0) cnh[code] = 0.5f * s;
}

// -------- MFMA VQ: argmax_k (z.c_k - 0.5|c_k|^2), 2-way bf16 split --------
// block 256 thr = 4 waves; wave = 32 rows (2 row-groups of 16); z in registers.
__global__ __launch_bounds__(256) void vq_mfma_kernel(
    const float* __restrict__ z, const unsigned short* __restrict__ cbh,
    const unsigned short* __restrict__ cbl, const float* __restrict__ cnh,
    int* __restrict__ ids) {
  __shared__ float cn_sh[1024];
  const int tid = threadIdx.x;
  const int lane = tid & 63;
  const int w = tid >> 6;
  const int q = lane >> 4;
  const int rbase = blockIdx.x * 128 + w * 32;
  for (int i = tid; i < 1024; i += 256) cn_sh[i] = cnh[i];
  __syncthreads();

  // z rows -> B-fragments (hi/lo): B[k][n], n=lane&15 (row), k=q*8+j (+32*ec)
  bf16x8 zh[2][8], zl[2][8];
  #pragma unroll
  for (int g = 0; g < 2; ++g) {
    const int row = rbase + g * 16 + (lane & 15);
    const float* zr = z + (size_t)row * 256 + q * 8;
    #pragma unroll
    for (int ec = 0; ec < 8; ++ec) {
      const f32x4 v0 = *(const f32x4*)(zr + ec * 32);
      const f32x4 v1 = *(const f32x4*)(zr + ec * 32 + 4);
      u16x8 h, l;
      #pragma unroll
      for (int j = 0; j < 4; ++j) {
        unsigned short a, b;
        split2(v0[j], a, b); h[j] = a; l[j] = b;
        split2(v1[j], a, b); h[4 + j] = a; l[4 + j] = b;
      }
      zh[g][ec] = (bf16x8)h;
      zl[g][ec] = (bf16x8)l;
    }
  }

  float best[2] = {-3.4e38f, -3.4e38f};
  int bidx[2] = {0, 0};
  const unsigned short* ah0 = cbh + ((size_t)(lane & 15)) * 256 + q * 8;
  const unsigned short* al0 = cbl + ((size_t)(lane & 15)) * 256 + q * 8;

  for (int cg = 0; cg < 64; ++cg) {
    const unsigned short* ah = ah0 + (size_t)cg * 16 * 256;
    const unsigned short* al = al0 + (size_t)cg * 16 * 256;
    f32x4 ahh[2], ahl[2], alh[2];     // 6 independent MFMA chains
    #pragma unroll
    for (int g = 0; g < 2; ++g) {
      ahh[g] = (f32x4){0.f, 0.f, 0.f, 0.f};
      ahl[g] = (f32x4){0.f, 0.f, 0.f, 0.f};
      alh[g] = (f32x4){0.f, 0.f, 0.f, 0.f};
    }
    #pragma unroll
    for (int ec = 0; ec < 8; ++ec) {
      const bf16x8 Ah = *(const bf16x8*)(ah + ec * 32);
      const bf16x8 Al = *(const bf16x8*)(al + ec * 32);
      #pragma unroll
      for (int g = 0; g < 2; ++g) {
        ahh[g] = __builtin_amdgcn_mfma_f32_16x16x32_bf16(Ah, zh[g][ec], ahh[g], 0, 0, 0);
        ahl[g] = __builtin_amdgcn_mfma_f32_16x16x32_bf16(Ah, zl[g][ec], ahl[g], 0, 0, 0);
        alh[g] = __builtin_amdgcn_mfma_f32_16x16x32_bf16(Al, zh[g][ec], alh[g], 0, 0, 0);
      }
    }
    // D[m][n]: n = lane&15 (z-row), m = q*4 + r (code within group)
    const f32x4 cn = *(const f32x4*)&cn_sh[cg * 16 + q * 4];
    #pragma unroll
    for (int g = 0; g < 2; ++g) {
      #pragma unroll
      for (int r = 0; r < 4; ++r) {
        const float s = (ahh[g][r] + ahl[g][r]) + alh[g][r] - cn[r];
        const int code = cg * 16 + q * 4 + r;
        if (s > best[g]) { best[g] = s; bidx[g] = code; }
      }
    }
  }
  // reduce across the 4 q-groups holding the same z-row
  #pragma unroll
  for (int g = 0; g < 2; ++g) {
    #pragma unroll
    for (int off = 16; off <= 32; off <<= 1) {
      const float ov = __shfl_xor(best[g], off, 64);
      const int oi = __shfl_xor(bidx[g], off, 64);
      if (ov > best[g] || (ov == best[g] && oi < bidx[g])) { best[g] = ov; bidx[g] = oi; }
    }
  }
  if (q == 0) {
    #pragma unroll
    for (int g = 0; g < 2; ++g) ids[rbase + g * 16 + lane] = bidx[g];
  }
}

// -------- gather z_q = codebook[ids] (r8 verbatim) --------
__global__ __launch_bounds__(256) void gather_kernel(
    const int* __restrict__ ids, const float* __restrict__ cb,
    float* __restrict__ zq) {
  const int row = blockIdx.x * 4 + (threadIdx.x >> 6);
  const int lane = threadIdx.x & 63;
  const int id = ids[row];
  const float4 v = *(const float4*)&cb[(size_t)id * E_ + lane * 4];
  *(float4*)&zq[(size_t)row * E_ + lane * 4] = v;
}

extern "C" void kernel_launch(void* const* d_in, const int* in_sizes, int n_in,
                              void* d_out, int out_size, void* d_ws, size_t ws_size,
                              hipStream_t stream) {
  const float* x   = (const float*)d_in[0];
  const float* w1  = (const float*)d_in[1];
  const float* b1  = (const float*)d_in[2];
  const float* g1  = (const float*)d_in[3];
  const float* be1 = (const float*)d_in[4];
  const float* w2  = (const float*)d_in[5];
  const float* b2  = (const float*)d_in[6];
  const float* g2  = (const float*)d_in[7];
  const float* be2 = (const float*)d_in[8];
  const float* w3  = (const float*)d_in[9];
  const float* b3  = (const float*)d_in[10];
  const float* g3  = (const float*)d_in[11];
  const float* be3 = (const float*)d_in[12];
  const float* w4  = (const float*)d_in[13];
  const float* b4  = (const float*)d_in[14];
  const float* cb  = (const float*)d_in[15];

  // r3/r8-proven ws map: all usage < 655360 bytes.
  char* ws = (char*)d_ws;
  float* tailA  = (float*)(ws);                 // (B,E) 32KB, reused h1/h3
  float* scale1 = (float*)(ws + 40960);  float* shift1 = (float*)(ws + 45056);
  float* scale2 = (float*)(ws + 49152);  float* shift2 = (float*)(ws + 53248);
  float* scale3 = (float*)(ws + 57344);  float* shift3 = (float*)(ws + 61440);
  float* cnh    = (float*)(ws + 65536);         // 4KB
  int*   ids    = (int*)(ws + 131072);          // 512KB

  float* half1 = (float*)d_out;                 // ends as z_e (B,T,E) f32
  float* half2 = half1 + (size_t)33554432;      // ends as z_q (B,T,E) f32
  // split codebook lives in half2 between conv4 and gather (h3 dead there)
  unsigned short* cbh = (unsigned short*)half2;             // 512KB
  unsigned short* cbl = (unsigned short*)half2 + 262144;    // 512KB

  // h1 -> half2 (+tail)
  conv1_kernel<<<dim3(17, 32), 256, 0, stream>>>(x, w1, b1, half2, tailA);
  bnstats_kernel<<<256, 256, 0, stream>>>(half2, tailA, g1, be1, scale1, shift1);
  // h2 -> half1
  conv_mid<0><<<dim3(32, 2, 32), 256, 0, stream>>>(half2, tailA, w2, b2, scale1, shift1,
                                                   half1, nullptr, 1);
  bnstats_kernel<<<256, 256, 0, stream>>>(half1, nullptr, g2, be2, scale2, shift2);
  // h3 -> half2 (+tail), h1 dead
  conv_mid<1><<<dim3(33, 2, 32), 256, 0, stream>>>(half1, nullptr, w3, b3, scale2, shift2,
                                                   half2, tailA, 2);
  bnstats_kernel<<<256, 256, 0, stream>>>(half2, tailA, g3, be3, scale3, shift3);
  // z -> half1 (final z_e), h2 dead
  conv_mid<2><<<dim3(32, 2, 32), 256, 0, stream>>>(half2, tailA, w4, b4, scale3, shift3,
                                                   half1, nullptr, 1);
  // h3 dead now: stage split codebook into half2, then VQ, then gather overwrites
  cbprep_kernel<<<256, 256, 0, stream>>>(cb, cbh, cbl, cnh);
  vq_mfma_kernel<<<1024, 256, 0, stream>>>(half1, cbh, cbl, cnh, ids);
  gather_kernel<<<32768, 256, 0, stream>>>(ids, cb, half2);
}

// Round 11
// 2048.700 us; speedup vs baseline: 6.4237x; 1.8995x over previous
//
#include <hip/hip_runtime.h>
#include <hip/hip_bf16.h>

// VQ-VAE encoder, round 11: r10 geometry (z_e-validated on HW) with 3-way
// RNE bf16 splits (6 MFMA/product, dropped terms ~2^-26) so VQ argmin ids
// match the fp32 reference (r10's 2-way split flipped near-tie ids).

#define B_   32
#define T_   4096
#define E_   256
#define CIN_ 12
#define LM_  4096

typedef __attribute__((ext_vector_type(4))) float f32x4;
typedef __attribute__((ext_vector_type(8))) short bf16x8;
typedef __attribute__((ext_vector_type(8))) unsigned short u16x8;

__device__ __forceinline__ unsigned int bf_rne(float v) {
  unsigned int u = __float_as_uint(v);
  return (u + 0x7fffu + ((u >> 16) & 1u)) >> 16;
}
__device__ __forceinline__ void split2(float v, unsigned short& h, unsigned short& l) {
  unsigned int hu = bf_rne(v);
  h = (unsigned short)hu;
  l = (unsigned short)bf_rne(v - __uint_as_float(hu << 16));
}
// 3-way RNE split: v ≈ a + b + c, residual ~2^-27 |v|
__device__ __forceinline__ void split3(float v, unsigned short& a,
                                       unsigned short& b, unsigned short& c) {
  unsigned int h = bf_rne(v);
  a = (unsigned short)h;
  float r1 = v - __uint_as_float(h << 16);
  unsigned int m = bf_rne(r1);
  b = (unsigned short)m;
  float r2 = r1 - __uint_as_float(m << 16);
  c = (unsigned short)bf_rne(r2);
}

// ---- prep_w: w (256,256,4) f32 -> frag-linear bf16 3-plane images ----
// img[slice=cc*4+kt][e][coff 0..31], channel c = cc*32+coff.
__global__ __launch_bounds__(256) void prep_w_kernel(
    const float* __restrict__ w, unsigned short* __restrict__ wh,
    unsigned short* __restrict__ wm, unsigned short* __restrict__ wl) {
  const int g = blockIdx.x * 256 + threadIdx.x;    // 262144
  const int coff  = g & 31;
  const int e     = (g >> 5) & 255;
  const int slice = g >> 13;                        // 0..31
  const int cc = slice >> 2, kt = slice & 3;
  const int c = cc * 32 + coff;
  unsigned short h, m, l;
  split3(w[(size_t)e * 1024 + (size_t)c * 4 + kt], h, m, l);
  const size_t o = (size_t)slice * 8192 + (size_t)e * 32 + coff;
  wh[o] = h; wm[o] = m; wl[o] = l;
}

// ---------------- conv1 (r8/r9 verbatim) ----------------
__global__ __launch_bounds__(256) void conv1_kernel(
    const float* __restrict__ x, const float* __restrict__ w1,
    const float* __restrict__ b1, float* __restrict__ out_main,
    float* __restrict__ out_tail) {
  __shared__ __align__(16) float xs[259][12];
  __shared__ __align__(16) float wsh[E_ * 48];
  __shared__ float bs[E_];
  const int tid = threadIdx.x;
  const int b = blockIdx.y;
  const int l0 = blockIdx.x * 256;
  for (int idx = tid; idx < 259 * 12; idx += 256) {
    int r = idx / 12, c = idx - r * 12;
    int t = l0 - 2 + r;
    xs[r][c] = (t >= 0 && t < T_) ? x[((size_t)b * T_ + t) * CIN_ + c] : 0.f;
  }
  for (int idx = tid; idx < E_ * 48; idx += 256) wsh[idx] = w1[idx];
  bs[tid] = b1[tid];
  __syncthreads();
  float xr[4][12];
  #pragma unroll
  for (int r = 0; r < 4; ++r)
    #pragma unroll
    for (int c = 0; c < 12; ++c) xr[r][c] = xs[tid + r][c];
  const int l = l0 + tid;
  for (int e = 0; e < E_; ++e) {
    float acc = bs[e];
    #pragma unroll
    for (int c = 0; c < 12; ++c) {
      const float4 wv = *(const float4*)&wsh[e * 48 + c * 4];
      acc += wv.x * xr[0][c] + wv.y * xr[1][c] + wv.z * xr[2][c] + wv.w * xr[3][c];
    }
    if (l < LM_)       out_main[((size_t)b * E_ + e) * LM_ + l] = acc;
    else if (l == LM_) out_tail[(size_t)b * E_ + e] = acc;
  }
}

// -------- BN train stats (r8/r9 verbatim) --------
__global__ __launch_bounds__(256) void bnstats_kernel(
    const float* __restrict__ hmain, const float* __restrict__ htail,
    const float* __restrict__ g, const float* __restrict__ be,
    float* __restrict__ scale, float* __restrict__ shift) {
  const int c = blockIdx.x, tid = threadIdx.x;
  const int Ltot = htail ? (LM_ + 1) : LM_;
  double s = 0.0, s2 = 0.0;
  for (int b = 0; b < B_; ++b) {
    const float* p = hmain + ((size_t)b * E_ + c) * LM_;
    for (int t = tid; t < Ltot; t += 256) {
      float v = (t < LM_) ? p[t] : htail[(size_t)b * E_ + c];
      s += v; s2 += (double)v * (double)v;
    }
  }
  __shared__ double sh[256], sh2[256];
  sh[tid] = s; sh2[tid] = s2; __syncthreads();
  for (int off = 128; off > 0; off >>= 1) {
    if (tid < off) { sh[tid] += sh[tid + off]; sh2[tid] += sh2[tid + off]; }
    __syncthreads();
  }
  if (tid == 0) {
    double N = (double)B_ * (double)Ltot;
    double m = sh[0] / N, var = sh2[0] / N - m * m;
    double a = (double)g[c] / sqrt(var + 1e-5);
    scale[c] = (float)a;
    shift[c] = (float)((double)be[c] - m * a);
  }
}

// -------- MFMA conv 256->256 k=4, 3-way split. Block 128e x 128l, 4 waves. --------
template <int MODE>
__global__ __launch_bounds__(256) void conv_mfma(
    const float* __restrict__ in_main, const float* __restrict__ in_tail,
    const unsigned short* __restrict__ wh, const unsigned short* __restrict__ wm,
    const unsigned short* __restrict__ wl, const float* __restrict__ bias,
    const float* __restrict__ scale, const float* __restrict__ shift,
    float* __restrict__ out, float* __restrict__ out_tail, int pad) {
  __shared__ __align__(16) char XhB[132 * 64];   // [u][32 bf16], slot-swizzled
  __shared__ __align__(16) char XmB[132 * 64];
  __shared__ __align__(16) char XlB[132 * 64];
  __shared__ float sc_sh[E_], sf_sh[E_];
  const int tid = threadIdx.x, lane = tid & 63, wv = tid >> 6;
  const int q = lane >> 4, n16 = lane & 15;
  const int b = blockIdx.z, e0 = blockIdx.y * 128, l0 = blockIdx.x * 128;
  const int eB = e0 + (wv & 1) * 64;   // wave e-base
  const int lB = (wv >> 1) * 64;       // wave l-offset within tile
  sc_sh[tid] = scale[tid]; sf_sh[tid] = shift[tid];

  f32x4 acc[4][4];
  #pragma unroll
  for (int i = 0; i < 4; ++i)
    #pragma unroll
    for (int j = 0; j < 4; ++j) acc[i][j] = (f32x4){0.f, 0.f, 0.f, 0.f};

  const float* inb = in_main + (size_t)b * E_ * LM_;
  const float* intb = in_tail ? (in_tail + (size_t)b * E_) : nullptr;

  for (int cc = 0; cc < 8; ++cc) {
    __syncthreads();                   // prior LDS reads done; sc_sh ready (iter 0)
    // ---- stage X: 528 tasks = uquad(33) x cpair(16); BN+ReLU+split3 ----
    for (int idx = tid; idx < 528; idx += 256) {
      const int cp = idx & 15, uq = idx >> 4;
      const int c = cc * 32 + cp * 2;
      const int u0 = uq * 4;
      const int lb = l0 - pad + u0;
      const float* pa = inb + (size_t)c * LM_;
      const float* pb = pa + LM_;
      const float sca = sc_sh[c], sfa = sf_sh[c];
      const float scb = sc_sh[c + 1], sfb = sf_sh[c + 1];
      float fa[4], fb[4];
      if (lb >= 0 && lb + 3 < LM_) {
        const f32x4 va = *(const f32x4*)(pa + lb);
        const f32x4 vb = *(const f32x4*)(pb + lb);
        #pragma unroll
        for (int s = 0; s < 4; ++s) {
          fa[s] = fmaxf(fmaf(va[s], sca, sfa), 0.f);
          fb[s] = fmaxf(fmaf(vb[s], scb, sfb), 0.f);
        }
      } else {
        #pragma unroll
        for (int s = 0; s < 4; ++s) {
          const int l = lb + s;
          float oa = 0.f, ob = 0.f;
          if (l >= 0 && l < LM_) {
            oa = fmaxf(fmaf(pa[l], sca, sfa), 0.f);
            ob = fmaxf(fmaf(pb[l], scb, sfb), 0.f);
          } else if (l == LM_ && intb) {
            oa = fmaxf(fmaf(intb[c], sca, sfa), 0.f);
            ob = fmaxf(fmaf(intb[c + 1], scb, sfb), 0.f);
          }
          fa[s] = oa; fb[s] = ob;
        }
      }
      const int cg = cp >> 2;              // channel-group (8ch) 0..3
      const int cb4 = (cp & 3) * 4;        // dword offset within 16B slot
      #pragma unroll
      for (int s = 0; s < 4; ++s) {
        const int u = u0 + s;
        unsigned short ha, ma, la, hb, mb, lb2;
        split3(fa[s], ha, ma, la);
        split3(fb[s], hb, mb, lb2);
        const int off = u * 64 + ((cg ^ ((u >> 1) & 3)) << 4) + cb4;
        *(unsigned int*)(XhB + off) = (unsigned int)ha | ((unsigned int)hb << 16);
        *(unsigned int*)(XmB + off) = (unsigned int)ma | ((unsigned int)mb << 16);
        *(unsigned int*)(XlB + off) = (unsigned int)la | ((unsigned int)lb2 << 16);
      }
    }
    __syncthreads();                   // X ready
    // ---- MFMA: per tap, A direct from global images, B from LDS ----
    for (int kt = 0; kt < 4; ++kt) {
      bf16x8 Bh[4], Bm[4], Bl[4];
      #pragma unroll
      for (int ni = 0; ni < 4; ++ni) {
        const int u = lB + ni * 16 + n16 + kt;
        const int off = u * 64 + ((q ^ ((u >> 1) & 3)) << 4);
        Bh[ni] = *(const bf16x8*)(XhB + off);
        Bm[ni] = *(const bf16x8*)(XmB + off);
        Bl[ni] = *(const bf16x8*)(XlB + off);
      }
      const size_t so = (size_t)(cc * 4 + kt) * 8192 + (size_t)q * 8;
      #pragma unroll
      for (int mi = 0; mi < 4; ++mi) {
        const size_t o = so + (size_t)(eB + mi * 16 + n16) * 32;
        const bf16x8 Ah = *(const bf16x8*)(wh + o);
        const bf16x8 Am = *(const bf16x8*)(wm + o);
        const bf16x8 Al = *(const bf16x8*)(wl + o);
        #pragma unroll
        for (int ni = 0; ni < 4; ++ni) {
          acc[mi][ni] = __builtin_amdgcn_mfma_f32_16x16x32_bf16(Ah, Bh[ni], acc[mi][ni], 0, 0, 0);
          acc[mi][ni] = __builtin_amdgcn_mfma_f32_16x16x32_bf16(Ah, Bm[ni], acc[mi][ni], 0, 0, 0);
          acc[mi][ni] = __builtin_amdgcn_mfma_f32_16x16x32_bf16(Am, Bh[ni], acc[mi][ni], 0, 0, 0);
          acc[mi][ni] = __builtin_amdgcn_mfma_f32_16x16x32_bf16(Ah, Bl[ni], acc[mi][ni], 0, 0, 0);
          acc[mi][ni] = __builtin_amdgcn_mfma_f32_16x16x32_bf16(Al, Bh[ni], acc[mi][ni], 0, 0, 0);
          acc[mi][ni] = __builtin_amdgcn_mfma_f32_16x16x32_bf16(Am, Bm[ni], acc[mi][ni], 0, 0, 0);
        }
      }
    }
  }

  // ---- epilogue: D row = e (q*4+reg), D col = l (n16) ----
  #pragma unroll
  for (int mi = 0; mi < 4; ++mi) {
    const int eb4 = eB + mi * 16 + q * 4;
    const f32x4 bv = *(const f32x4*)(bias + eb4);
    #pragma unroll
    for (int ni = 0; ni < 4; ++ni) {
      const int col = l0 + lB + ni * 16 + n16;
      const f32x4 r = acc[mi][ni] + bv;
      if constexpr (MODE == 0) {
        #pragma unroll
        for (int rr = 0; rr < 4; ++rr)
          out[((size_t)b * E_ + eb4 + rr) * LM_ + col] = r[rr];
      } else if constexpr (MODE == 1) {
        if (col < LM_) {
          #pragma unroll
          for (int rr = 0; rr < 4; ++rr)
            out[((size_t)b * E_ + eb4 + rr) * LM_ + col] = r[rr];
        } else if (col == LM_) {
          #pragma unroll
          for (int rr = 0; rr < 4; ++rr)
            out_tail[(size_t)b * E_ + eb4 + rr] = r[rr];
        }
      } else {
        #pragma unroll
        for (int rr = 0; rr < 4; ++rr)
          out[((size_t)b * T_ + col) * E_ + eb4 + rr] = r[rr];
      }
    }
  }
}

// -------- cbprep (r9 verbatim) --------
__global__ __launch_bounds__(256) void cbprep_kernel(
    const float* __restrict__ cb, unsigned short* __restrict__ cbh,
    unsigned short* __restrict__ cbl, float* __restrict__ cnh) {
  const int code = blockIdx.x * 4 + (threadIdx.x >> 6);
  const int lane = threadIdx.x & 63;
  const f32x4 v = *(const f32x4*)&cb[(size_t)code * E_ + lane * 4];
  ushort4 h, l;
  split2(v.x, h.x, l.x); split2(v.y, h.y, l.y);
  split2(v.z, h.z, l.z); split2(v.w, h.w, l.w);
  *(ushort4*)&cbh[(size_t)code * E_ + lane * 4] = h;
  *(ushort4*)&cbl[(size_t)code * E_ + lane * 4] = l;
  float s = v.x * v.x + v.y * v.y + v.z * v.z + v.w * v.w;
  for (int off = 32; off > 0; off >>= 1) s += __shfl_xor(s, off, 64);
  if (lane == 0) cnh[code] = 0.5f * s;
}

// -------- MFMA VQ (r9 verbatim) --------
__global__ __launch_bounds__(256) void vq_mfma_kernel(
    const float* __restrict__ z, const unsigned short* __restrict__ cbh,
    const unsigned short* __restrict__ cbl, const float* __restrict__ cnh,
    int* __restrict__ ids) {
  __shared__ float cn_sh[1024];
  const int tid = threadIdx.x;
  const int lane = tid & 63;
  const int w = tid >> 6;
  const int q = lane >> 4;
  const int rbase = blockIdx.x * 128 + w * 32;
  for (int i = tid; i < 1024; i += 256) cn_sh[i] = cnh[i];
  __syncthreads();

  bf16x8 zh[2][8], zl[2][8];
  #pragma unroll
  for (int g = 0; g < 2; ++g) {
    const int row = rbase + g * 16 + (lane & 15);
    const float* zr = z + (size_t)row * 256 + q * 8;
    #pragma unroll
    for (int ec = 0; ec < 8; ++ec) {
      const f32x4 v0 = *(const f32x4*)(zr + ec * 32);
      const f32x4 v1 = *(const f32x4*)(zr + ec * 32 + 4);
      u16x8 h, l;
      #pragma unroll
      for (int j = 0; j < 4; ++j) {
        unsigned short a, b;
        split2(v0[j], a, b); h[j] = a; l[j] = b;
        split2(v1[j], a, b); h[4 + j] = a; l[4 + j] = b;
      }
      zh[g][ec] = (bf16x8)h;
      zl[g][ec] = (bf16x8)l;
    }
  }

  float best[2] = {-3.4e38f, -3.4e38f};
  int bidx[2] = {0, 0};
  const unsigned short* ah0 = cbh + ((size_t)(lane & 15)) * 256 + q * 8;
  const unsigned short* al0 = cbl + ((size_t)(lane & 15)) * 256 + q * 8;

  for (int cg = 0; cg < 64; ++cg) {
    const unsigned short* ah = ah0 + (size_t)cg * 16 * 256;
    const unsigned short* al = al0 + (size_t)cg * 16 * 256;
    f32x4 ahh[2], ahl[2], alh[2];
    #pragma unroll
    for (int g = 0; g < 2; ++g) {
      ahh[g] = (f32x4){0.f, 0.f, 0.f, 0.f};
      ahl[g] = (f32x4){0.f, 0.f, 0.f, 0.f};
      alh[g] = (f32x4){0.f, 0.f, 0.f, 0.f};
    }
    #pragma unroll
    for (int ec = 0; ec < 8; ++ec) {
      const bf16x8 Ah = *(const bf16x8*)(ah + ec * 32);
      const bf16x8 Al = *(const bf16x8*)(al + ec * 32);
      #pragma unroll
      for (int g = 0; g < 2; ++g) {
        ahh[g] = __builtin_amdgcn_mfma_f32_16x16x32_bf16(Ah, zh[g][ec], ahh[g], 0, 0, 0);
        ahl[g] = __builtin_amdgcn_mfma_f32_16x16x32_bf16(Ah, zl[g][ec], ahl[g], 0, 0, 0);
        alh[g] = __builtin_amdgcn_mfma_f32_16x16x32_bf16(Al, zh[g][ec], alh[g], 0, 0, 0);
      }
    }
    const f32x4 cn = *(const f32x4*)&cn_sh[cg * 16 + q * 4];
    #pragma unroll
    for (int g = 0; g < 2; ++g) {
      #pragma unroll
      for (int r = 0; r < 4; ++r) {
        const float s = (ahh[g][r] + ahl[g][r]) + alh[g][r] - cn[r];
        const int code = cg * 16 + q * 4 + r;
        if (s > best[g]) { best[g] = s; bidx[g] = code; }
      }
    }
  }
  #pragma unroll
  for (int g = 0; g < 2; ++g) {
    #pragma unroll
    for (int off = 16; off <= 32; off <<= 1) {
      const float ov = __shfl_xor(best[g], off, 64);
      const int oi = __shfl_xor(bidx[g], off, 64);
      if (ov > best[g] || (ov == best[g] && oi < bidx[g])) { best[g] = ov; bidx[g] = oi; }
    }
  }
  if (q == 0) {
    #pragma unroll
    for (int g = 0; g < 2; ++g) ids[rbase + g * 16 + lane] = bidx[g];
  }
}

// -------- gather (r9 verbatim) --------
__global__ __launch_bounds__(256) void gather_kernel(
    const int* __restrict__ ids, const float* __restrict__ cb,
    float* __restrict__ zq) {
  const int row = blockIdx.x * 4 + (threadIdx.x >> 6);
  const int lane = threadIdx.x & 63;
  const int id = ids[row];
  const float4 v = *(const float4*)&cb[(size_t)id * E_ + lane * 4];
  *(float4*)&zq[(size_t)row * E_ + lane * 4] = v;
}

extern "C" void kernel_launch(void* const* d_in, const int* in_sizes, int n_in,
                              void* d_out, int out_size, void* d_ws, size_t ws_size,
                              hipStream_t stream) {
  const float* x   = (const float*)d_in[0];
  const float* w1  = (const float*)d_in[1];
  const float* b1  = (const float*)d_in[2];
  const float* g1  = (const float*)d_in[3];
  const float* be1 = (const float*)d_in[4];
  const float* w2  = (const float*)d_in[5];
  const float* b2  = (const float*)d_in[6];
  const float* g2  = (const float*)d_in[7];
  const float* be2 = (const float*)d_in[8];
  const float* w3  = (const float*)d_in[9];
  const float* b3  = (const float*)d_in[10];
  const float* g3  = (const float*)d_in[11];
  const float* be3 = (const float*)d_in[12];
  const float* w4  = (const float*)d_in[13];
  const float* b4  = (const float*)d_in[14];
  const float* cb  = (const float*)d_in[15];

  char* ws = (char*)d_ws;
  float* tailA  = (float*)(ws);                 // (B,E) 32KB, reused h1/h3
  float* scale1 = (float*)(ws + 40960);  float* shift1 = (float*)(ws + 45056);
  float* scale2 = (float*)(ws + 49152);  float* shift2 = (float*)(ws + 53248);
  float* scale3 = (float*)(ws + 57344);  float* shift3 = (float*)(ws + 61440);
  float* cnh    = (float*)(ws + 65536);         // 4KB
  int*   ids    = (int*)(ws + 131072);          // 512KB
  // W images @ 1MiB+: 3 planes x 512KB per layer
  const size_t MB = 1u << 20;
  unsigned short* wh2 = (unsigned short*)(ws + MB);
  unsigned short* wm2 = (unsigned short*)(ws + MB + 524288u);
  unsigned short* wl2 = (unsigned short*)(ws + MB + 1048576u);
  unsigned short* wh3 = (unsigned short*)(ws + MB + 1572864u);
  unsigned short* wm3 = (unsigned short*)(ws + MB + 2097152u);
  unsigned short* wl3 = (unsigned short*)(ws + MB + 2621440u);
  unsigned short* wh4 = (unsigned short*)(ws + MB + 3145728u);
  unsigned short* wm4 = (unsigned short*)(ws + MB + 3670016u);
  unsigned short* wl4 = (unsigned short*)(ws + MB + 4194304u);

  float* half1 = (float*)d_out;                 // ends as z_e (B,T,E) f32
  float* half2 = half1 + (size_t)33554432;      // ends as z_q (B,T,E) f32
  unsigned short* cbh = (unsigned short*)half2;             // 512KB (post-conv4)
  unsigned short* cbl = (unsigned short*)half2 + 262144;    // 512KB

  prep_w_kernel<<<1024, 256, 0, stream>>>(w2, wh2, wm2, wl2);
  prep_w_kernel<<<1024, 256, 0, stream>>>(w3, wh3, wm3, wl3);
  prep_w_kernel<<<1024, 256, 0, stream>>>(w4, wh4, wm4, wl4);

  // h1 -> half2 (+tail)
  conv1_kernel<<<dim3(17, 32), 256, 0, stream>>>(x, w1, b1, half2, tailA);
  bnstats_kernel<<<256, 256, 0, stream>>>(half2, tailA, g1, be1, scale1, shift1);
  // h2 -> half1
  conv_mfma<0><<<dim3(32, 2, 32), 256, 0, stream>>>(half2, tailA, wh2, wm2, wl2, b2,
                                                    scale1, shift1, half1, nullptr, 1);
  bnstats_kernel<<<256, 256, 0, stream>>>(half1, nullptr, g2, be2, scale2, shift2);
  // h3 -> half2 (+tail), h1 dead
  conv_mfma<1><<<dim3(33, 2, 32), 256, 0, stream>>>(half1, nullptr, wh3, wm3, wl3, b3,
                                                    scale2, shift2, half2, tailA, 2);
  bnstats_kernel<<<256, 256, 0, stream>>>(half2, tailA, g3, be3, scale3, shift3);
  // z -> half1 (= z_e), h2 dead
  conv_mfma<2><<<dim3(32, 2, 32), 256, 0, stream>>>(half2, tailA, wh4, wm4, wl4, b4,
                                                    scale3, shift3, half1, nullptr, 1);
  // h3 dead: split codebook into half2, VQ, gather overwrites
  cbprep_kernel<<<256, 256, 0, stream>>>(cb, cbh, cbl, cnh);
  vq_mfma_kernel<<<1024, 256, 0, stream>>>(half1, cbh, cbl, cnh, ids);
  gather_kernel<<<32768, 256, 0, stream>>>(ids, cb, half2);
}

// Round 12
// 1462.167 us; speedup vs baseline: 9.0004x; 1.4011x over previous
//
#include <hip/hip_runtime.h>
#include <hip/hip_bf16.h>

// VQ-VAE encoder, round 12: r11 (proven, 2049us) + LDS-staged double-buffered
// vq (4x less L2 traffic, T14 async-stage) + two-pass BN stats.
// Convs/conv1/prep/cbprep/gather verbatim from r11.

#define B_   32
#define T_   4096
#define E_   256
#define CIN_ 12
#define LM_  4096

typedef __attribute__((ext_vector_type(4))) float f32x4;
typedef __attribute__((ext_vector_type(8))) short bf16x8;
typedef __attribute__((ext_vector_type(8))) unsigned short u16x8;

__device__ __forceinline__ unsigned int bf_rne(float v) {
  unsigned int u = __float_as_uint(v);
  return (u + 0x7fffu + ((u >> 16) & 1u)) >> 16;
}
__device__ __forceinline__ void split2(float v, unsigned short& h, unsigned short& l) {
  unsigned int hu = bf_rne(v);
  h = (unsigned short)hu;
  l = (unsigned short)bf_rne(v - __uint_as_float(hu << 16));
}
__device__ __forceinline__ void split3(float v, unsigned short& a,
                                       unsigned short& b, unsigned short& c) {
  unsigned int h = bf_rne(v);
  a = (unsigned short)h;
  float r1 = v - __uint_as_float(h << 16);
  unsigned int m = bf_rne(r1);
  b = (unsigned short)m;
  float r2 = r1 - __uint_as_float(m << 16);
  c = (unsigned short)bf_rne(r2);
}

// ---- prep_w (r11 verbatim) ----
__global__ __launch_bounds__(256) void prep_w_kernel(
    const float* __restrict__ w, unsigned short* __restrict__ wh,
    unsigned short* __restrict__ wm, unsigned short* __restrict__ wl) {
  const int g = blockIdx.x * 256 + threadIdx.x;
  const int coff  = g & 31;
  const int e     = (g >> 5) & 255;
  const int slice = g >> 13;
  const int cc = slice >> 2, kt = slice & 3;
  const int c = cc * 32 + coff;
  unsigned short h, m, l;
  split3(w[(size_t)e * 1024 + (size_t)c * 4 + kt], h, m, l);
  const size_t o = (size_t)slice * 8192 + (size_t)e * 32 + coff;
  wh[o] = h; wm[o] = m; wl[o] = l;
}

// ---- conv1 (r11 verbatim) ----
__global__ __launch_bounds__(256) void conv1_kernel(
    const float* __restrict__ x, const float* __restrict__ w1,
    const float* __restrict__ b1, float* __restrict__ out_main,
    float* __restrict__ out_tail) {
  __shared__ __align__(16) float xs[259][12];
  __shared__ __align__(16) float wsh[E_ * 48];
  __shared__ float bs[E_];
  const int tid = threadIdx.x;
  const int b = blockIdx.y;
  const int l0 = blockIdx.x * 256;
  for (int idx = tid; idx < 259 * 12; idx += 256) {
    int r = idx / 12, c = idx - r * 12;
    int t = l0 - 2 + r;
    xs[r][c] = (t >= 0 && t < T_) ? x[((size_t)b * T_ + t) * CIN_ + c] : 0.f;
  }
  for (int idx = tid; idx < E_ * 48; idx += 256) wsh[idx] = w1[idx];
  bs[tid] = b1[tid];
  __syncthreads();
  float xr[4][12];
  #pragma unroll
  for (int r = 0; r < 4; ++r)
    #pragma unroll
    for (int c = 0; c < 12; ++c) xr[r][c] = xs[tid + r][c];
  const int l = l0 + tid;
  for (int e = 0; e < E_; ++e) {
    float acc = bs[e];
    #pragma unroll
    for (int c = 0; c < 12; ++c) {
      const float4 wv = *(const float4*)&wsh[e * 48 + c * 4];
      acc += wv.x * xr[0][c] + wv.y * xr[1][c] + wv.z * xr[2][c] + wv.w * xr[3][c];
    }
    if (l < LM_)       out_main[((size_t)b * E_ + e) * LM_ + l] = acc;
    else if (l == LM_) out_tail[(size_t)b * E_ + e] = acc;
  }
}

// ---- BN stats two-pass: pass1 grid 2048 = c*8 + sl ----
__global__ __launch_bounds__(256) void bn_pass1(
    const float* __restrict__ hmain, const float* __restrict__ htail,
    float* __restrict__ psum, float* __restrict__ psq) {
  const int bx = blockIdx.x;
  const int c = bx >> 3, sl = bx & 7;
  const int tid = threadIdx.x;
  float s = 0.f, s2 = 0.f;
  for (int b = 0; b < B_; ++b) {
    const float* p = hmain + ((size_t)b * E_ + c) * LM_ + sl * 512;
    const float v0 = p[tid], v1 = p[tid + 256];
    s += v0 + v1;
    s2 += v0 * v0 + v1 * v1;
  }
  if (htail && sl == 7 && tid < B_) {
    const float v = htail[(size_t)tid * E_ + c];
    s += v; s2 += v * v;
  }
  __shared__ float sh[256], sh2[256];
  sh[tid] = s; sh2[tid] = s2; __syncthreads();
  for (int off = 128; off > 0; off >>= 1) {
    if (tid < off) { sh[tid] += sh[tid + off]; sh2[tid] += sh2[tid + off]; }
    __syncthreads();
  }
  if (tid == 0) { psum[bx] = sh[0]; psq[bx] = sh2[0]; }
}

__global__ __launch_bounds__(256) void bn_pass2(
    const float* __restrict__ psum, const float* __restrict__ psq,
    const float* __restrict__ g, const float* __restrict__ be,
    float* __restrict__ scale, float* __restrict__ shift, int hasTail) {
  const int c = threadIdx.x;
  double s = 0.0, s2 = 0.0;
  #pragma unroll
  for (int i = 0; i < 8; ++i) { s += psum[c * 8 + i]; s2 += psq[c * 8 + i]; }
  double N = (double)B_ * (double)(LM_ + hasTail);
  double m = s / N, var = s2 / N - m * m;
  double a = (double)g[c] / sqrt(var + 1e-5);
  scale[c] = (float)a;
  shift[c] = (float)((double)be[c] - m * a);
}

// ---- MFMA conv (r11 verbatim) ----
template <int MODE>
__global__ __launch_bounds__(256) void conv_mfma(
    const float* __restrict__ in_main, const float* __restrict__ in_tail,
    const unsigned short* __restrict__ wh, const unsigned short* __restrict__ wm,
    const unsigned short* __restrict__ wl, const float* __restrict__ bias,
    const float* __restrict__ scale, const float* __restrict__ shift,
    float* __restrict__ out, float* __restrict__ out_tail, int pad) {
  __shared__ __align__(16) char XhB[132 * 64];
  __shared__ __align__(16) char XmB[132 * 64];
  __shared__ __align__(16) char XlB[132 * 64];
  __shared__ float sc_sh[E_], sf_sh[E_];
  const int tid = threadIdx.x, lane = tid & 63, wv = tid >> 6;
  const int q = lane >> 4, n16 = lane & 15;
  const int b = blockIdx.z, e0 = blockIdx.y * 128, l0 = blockIdx.x * 128;
  const int eB = e0 + (wv & 1) * 64;
  const int lB = (wv >> 1) * 64;
  sc_sh[tid] = scale[tid]; sf_sh[tid] = shift[tid];

  f32x4 acc[4][4];
  #pragma unroll
  for (int i = 0; i < 4; ++i)
    #pragma unroll
    for (int j = 0; j < 4; ++j) acc[i][j] = (f32x4){0.f, 0.f, 0.f, 0.f};

  const float* inb = in_main + (size_t)b * E_ * LM_;
  const float* intb = in_tail ? (in_tail + (size_t)b * E_) : nullptr;

  for (int cc = 0; cc < 8; ++cc) {
    __syncthreads();
    for (int idx = tid; idx < 528; idx += 256) {
      const int cp = idx & 15, uq = idx >> 4;
      const int c = cc * 32 + cp * 2;
      const int u0 = uq * 4;
      const int lb = l0 - pad + u0;
      const float* pa = inb + (size_t)c * LM_;
      const float* pb = pa + LM_;
      const float sca = sc_sh[c], sfa = sf_sh[c];
      const float scb = sc_sh[c + 1], sfb = sf_sh[c + 1];
      float fa[4], fb[4];
      if (lb >= 0 && lb + 3 < LM_) {
        const f32x4 va = *(const f32x4*)(pa + lb);
        const f32x4 vb = *(const f32x4*)(pb + lb);
        #pragma unroll
        for (int s = 0; s < 4; ++s) {
          fa[s] = fmaxf(fmaf(va[s], sca, sfa), 0.f);
          fb[s] = fmaxf(fmaf(vb[s], scb, sfb), 0.f);
        }
      } else {
        #pragma unroll
        for (int s = 0; s < 4; ++s) {
          const int l = lb + s;
          float oa = 0.f, ob = 0.f;
          if (l >= 0 && l < LM_) {
            oa = fmaxf(fmaf(pa[l], sca, sfa), 0.f);
            ob = fmaxf(fmaf(pb[l], scb, sfb), 0.f);
          } else if (l == LM_ && intb) {
            oa = fmaxf(fmaf(intb[c], sca, sfa), 0.f);
            ob = fmaxf(fmaf(intb[c + 1], scb, sfb), 0.f);
          }
          fa[s] = oa; fb[s] = ob;
        }
      }
      const int cg = cp >> 2;
      const int cb4 = (cp & 3) * 4;
      #pragma unroll
      for (int s = 0; s < 4; ++s) {
        const int u = u0 + s;
        unsigned short ha, ma, la, hb, mb, lb2;
        split3(fa[s], ha, ma, la);
        split3(fb[s], hb, mb, lb2);
        const int off = u * 64 + ((cg ^ ((u >> 1) & 3)) << 4) + cb4;
        *(unsigned int*)(XhB + off) = (unsigned int)ha | ((unsigned int)hb << 16);
        *(unsigned int*)(XmB + off) = (unsigned int)ma | ((unsigned int)mb << 16);
        *(unsigned int*)(XlB + off) = (unsigned int)la | ((unsigned int)lb2 << 16);
      }
    }
    __syncthreads();
    for (int kt = 0; kt < 4; ++kt) {
      bf16x8 Bh[4], Bm[4], Bl[4];
      #pragma unroll
      for (int ni = 0; ni < 4; ++ni) {
        const int u = lB + ni * 16 + n16 + kt;
        const int off = u * 64 + ((q ^ ((u >> 1) & 3)) << 4);
        Bh[ni] = *(const bf16x8*)(XhB + off);
        Bm[ni] = *(const bf16x8*)(XmB + off);
        Bl[ni] = *(const bf16x8*)(XlB + off);
      }
      const size_t so = (size_t)(cc * 4 + kt) * 8192 + (size_t)q * 8;
      #pragma unroll
      for (int mi = 0; mi < 4; ++mi) {
        const size_t o = so + (size_t)(eB + mi * 16 + n16) * 32;
        const bf16x8 Ah = *(const bf16x8*)(wh + o);
        const bf16x8 Am = *(const bf16x8*)(wm + o);
        const bf16x8 Al = *(const bf16x8*)(wl + o);
        #pragma unroll
        for (int ni = 0; ni < 4; ++ni) {
          acc[mi][ni] = __builtin_amdgcn_mfma_f32_16x16x32_bf16(Ah, Bh[ni], acc[mi][ni], 0, 0, 0);
          acc[mi][ni] = __builtin_amdgcn_mfma_f32_16x16x32_bf16(Ah, Bm[ni], acc[mi][ni], 0, 0, 0);
          acc[mi][ni] = __builtin_amdgcn_mfma_f32_16x16x32_bf16(Am, Bh[ni], acc[mi][ni], 0, 0, 0);
          acc[mi][ni] = __builtin_amdgcn_mfma_f32_16x16x32_bf16(Ah, Bl[ni], acc[mi][ni], 0, 0, 0);
          acc[mi][ni] = __builtin_amdgcn_mfma_f32_16x16x32_bf16(Al, Bh[ni], acc[mi][ni], 0, 0, 0);
          acc[mi][ni] = __builtin_amdgcn_mfma_f32_16x16x32_bf16(Am, Bm[ni], acc[mi][ni], 0, 0, 0);
        }
      }
    }
  }

  #pragma unroll
  for (int mi = 0; mi < 4; ++mi) {
    const int eb4 = eB + mi * 16 + q * 4;
    const f32x4 bv = *(const f32x4*)(bias + eb4);
    #pragma unroll
    for (int ni = 0; ni < 4; ++ni) {
      const int col = l0 + lB + ni * 16 + n16;
      const f32x4 r = acc[mi][ni] + bv;
      if constexpr (MODE == 0) {
        #pragma unroll
        for (int rr = 0; rr < 4; ++rr)
          out[((size_t)b * E_ + eb4 + rr) * LM_ + col] = r[rr];
      } else if constexpr (MODE == 1) {
        if (col < LM_) {
          #pragma unroll
          for (int rr = 0; rr < 4; ++rr)
            out[((size_t)b * E_ + eb4 + rr) * LM_ + col] = r[rr];
        } else if (col == LM_) {
          #pragma unroll
          for (int rr = 0; rr < 4; ++rr)
            out_tail[(size_t)b * E_ + eb4 + rr] = r[rr];
        }
      } else {
        #pragma unroll
        for (int rr = 0; rr < 4; ++rr)
          out[((size_t)b * T_ + col) * E_ + eb4 + rr] = r[rr];
      }
    }
  }
}

// ---- cbprep (r11 verbatim) ----
__global__ __launch_bounds__(256) void cbprep_kernel(
    const float* __restrict__ cb, unsigned short* __restrict__ cbh,
    unsigned short* __restrict__ cbl, float* __restrict__ cnh) {
  const int code = blockIdx.x * 4 + (threadIdx.x >> 6);
  const int lane = threadIdx.x & 63;
  const f32x4 v = *(const f32x4*)&cb[(size_t)code * E_ + lane * 4];
  ushort4 h, l;
  split2(v.x, h.x, l.x); split2(v.y, h.y, l.y);
  split2(v.z, h.z, l.z); split2(v.w, h.w, l.w);
  *(ushort4*)&cbh[(size_t)code * E_ + lane * 4] = h;
  *(ushort4*)&cbl[(size_t)code * E_ + lane * 4] = l;
  float s = v.x * v.x + v.y * v.y + v.z * v.z + v.w * v.w;
  for (int off = 32; off > 0; off >>= 1) s += __shfl_xor(s, off, 64);
  if (lane == 0) cnh[code] = 0.5f * s;
}

// ---- MFMA VQ v2: LDS-staged codebook, double-buffered (T14 split) ----
// A-frag math identical to r9 (proven); A now served from swizzled LDS.
__global__ __launch_bounds__(256) void vq_mfma_kernel(
    const float* __restrict__ z, const unsigned short* __restrict__ cbh,
    const unsigned short* __restrict__ cbl, const float* __restrict__ cnh,
    int* __restrict__ ids) {
  __shared__ __align__(16) char cbLds[2][16384];   // [buf][hi 8KB | lo 8KB]
  __shared__ float cn_sh[1024];
  const int tid = threadIdx.x;
  const int lane = tid & 63;
  const int w = tid >> 6;
  const int q = lane >> 4;
  const int m15 = lane & 15;
  const int rbase = blockIdx.x * 128 + w * 32;
  for (int i = tid; i < 1024; i += 256) cn_sh[i] = cnh[i];

  // staging slot map: slot s (0..511) -> code=s>>5, col=s&31;
  // LDS byte = code*512 + ((col ^ (code&7))<<4). Global src = slot-linear.
  const int sc0 = tid >> 5, sl0 = tid & 31;             // slot tid
  const int sc1 = (tid + 256) >> 5, sl1 = (tid + 256) & 31;
  const int d0 = sc0 * 512 + (((sl0 ^ (sc0 & 7))) << 4);
  const int d1 = sc1 * 512 + (((sl1 ^ (sc1 & 7))) << 4);
  const u16x8* srcH = (const u16x8*)cbh;
  const u16x8* srcL = (const u16x8*)cbl;

  // prologue: stage cg=0 into buf0
  {
    u16x8 h0 = srcH[tid], h1 = srcH[tid + 256];
    u16x8 l0 = srcL[tid], l1 = srcL[tid + 256];
    *(u16x8*)(cbLds[0] + d0) = h0;
    *(u16x8*)(cbLds[0] + d1) = h1;
    *(u16x8*)(cbLds[0] + 8192 + d0) = l0;
    *(u16x8*)(cbLds[0] + 8192 + d1) = l1;
  }

  // z rows -> B-fragments (r9 verbatim)
  bf16x8 zh[2][8], zl[2][8];
  #pragma unroll
  for (int g = 0; g < 2; ++g) {
    const int row = rbase + g * 16 + m15;
    const float* zr = z + (size_t)row * 256 + q * 8;
    #pragma unroll
    for (int ec = 0; ec < 8; ++ec) {
      const f32x4 v0 = *(const f32x4*)(zr + ec * 32);
      const f32x4 v1 = *(const f32x4*)(zr + ec * 32 + 4);
      u16x8 h, l;
      #pragma unroll
      for (int j = 0; j < 4; ++j) {
        unsigned short a, b;
        split2(v0[j], a, b); h[j] = a; l[j] = b;
        split2(v1[j], a, b); h[4 + j] = a; l[4 + j] = b;
      }
      zh[g][ec] = (bf16x8)h;
      zl[g][ec] = (bf16x8)l;
    }
  }
  __syncthreads();

  float best[2] = {-3.4e38f, -3.4e38f};
  int bidx[2] = {0, 0};
  const int swz = (m15 & 7) << 4;
  const int rowOff = m15 * 512;

  for (int cg = 0; cg < 64; ++cg) {
    const int cur = cg & 1;
    u16x8 ph0, ph1, pl0, pl1;
    if (cg < 63) {                       // T14: issue next-chunk loads early
      const int sb = (cg + 1) * 512;
      ph0 = srcH[sb + tid]; ph1 = srcH[sb + tid + 256];
      pl0 = srcL[sb + tid]; pl1 = srcL[sb + tid + 256];
    }
    // compute cg from LDS buf[cur]
    const char* baseH = cbLds[cur];
    const char* baseL = cbLds[cur] + 8192;
    f32x4 ahh[2], ahl[2], alh[2];
    #pragma unroll
    for (int g = 0; g < 2; ++g) {
      ahh[g] = (f32x4){0.f, 0.f, 0.f, 0.f};
      ahl[g] = (f32x4){0.f, 0.f, 0.f, 0.f};
      alh[g] = (f32x4){0.f, 0.f, 0.f, 0.f};
    }
    #pragma unroll
    for (int ec = 0; ec < 8; ++ec) {
      const int co = rowOff + ((q * 16 + ec * 64) ^ swz);
      const bf16x8 Ah = *(const bf16x8*)(baseH + co);
      const bf16x8 Al = *(const bf16x8*)(baseL + co);
      #pragma unroll
      for (int g = 0; g < 2; ++g) {
        ahh[g] = __builtin_amdgcn_mfma_f32_16x16x32_bf16(Ah, zh[g][ec], ahh[g], 0, 0, 0);
        ahl[g] = __builtin_amdgcn_mfma_f32_16x16x32_bf16(Ah, zl[g][ec], ahl[g], 0, 0, 0);
        alh[g] = __builtin_amdgcn_mfma_f32_16x16x32_bf16(Al, zh[g][ec], alh[g], 0, 0, 0);
      }
    }
    const f32x4 cn = *(const f32x4*)&cn_sh[cg * 16 + q * 4];
    #pragma unroll
    for (int g = 0; g < 2; ++g) {
      #pragma unroll
      for (int r = 0; r < 4; ++r) {
        const float s = (ahh[g][r] + ahl[g][r]) + alh[g][r] - cn[r];
        const int code = cg * 16 + q * 4 + r;
        if (s > best[g]) { best[g] = s; bidx[g] = code; }
      }
    }
    if (cg < 63) {                       // write prefetched regs -> other buf
      char* nb = cbLds[cur ^ 1];
      *(u16x8*)(nb + d0) = ph0;
      *(u16x8*)(nb + d1) = ph1;
      *(u16x8*)(nb + 8192 + d0) = pl0;
      *(u16x8*)(nb + 8192 + d1) = pl1;
    }
    __syncthreads();
  }

  #pragma unroll
  for (int g = 0; g < 2; ++g) {
    #pragma unroll
    for (int off = 16; off <= 32; off <<= 1) {
      const float ov = __shfl_xor(best[g], off, 64);
      const int oi = __shfl_xor(bidx[g], off, 64);
      if (ov > best[g] || (ov == best[g] && oi < bidx[g])) { best[g] = ov; bidx[g] = oi; }
    }
  }
  if (q == 0) {
    #pragma unroll
    for (int g = 0; g < 2; ++g) ids[rbase + g * 16 + lane] = bidx[g];
  }
}

// ---- gather (r11 verbatim) ----
__global__ __launch_bounds__(256) void gather_kernel(
    const int* __restrict__ ids, const float* __restrict__ cb,
    float* __restrict__ zq) {
  const int row = blockIdx.x * 4 + (threadIdx.x >> 6);
  const int lane = threadIdx.x & 63;
  const int id = ids[row];
  const float4 v = *(const float4*)&cb[(size_t)id * E_ + lane * 4];
  *(float4*)&zq[(size_t)row * E_ + lane * 4] = v;
}

extern "C" void kernel_launch(void* const* d_in, const int* in_sizes, int n_in,
                              void* d_out, int out_size, void* d_ws, size_t ws_size,
                              hipStream_t stream) {
  const float* x   = (const float*)d_in[0];
  const float* w1  = (const float*)d_in[1];
  const float* b1  = (const float*)d_in[2];
  const float* g1  = (const float*)d_in[3];
  const float* be1 = (const float*)d_in[4];
  const float* w2  = (const float*)d_in[5];
  const float* b2  = (const float*)d_in[6];
  const float* g2  = (const float*)d_in[7];
  const float* be2 = (const float*)d_in[8];
  const float* w3  = (const float*)d_in[9];
  const float* b3  = (const float*)d_in[10];
  const float* g3  = (const float*)d_in[11];
  const float* be3 = (const float*)d_in[12];
  const float* w4  = (const float*)d_in[13];
  const float* b4  = (const float*)d_in[14];
  const float* cb  = (const float*)d_in[15];

  char* ws = (char*)d_ws;
  float* tailA  = (float*)(ws);                 // (B,E) 32KB, reused h1/h3
  float* scale1 = (float*)(ws + 40960);  float* shift1 = (float*)(ws + 45056);
  float* scale2 = (float*)(ws + 49152);  float* shift2 = (float*)(ws + 53248);
  float* scale3 = (float*)(ws + 57344);  float* shift3 = (float*)(ws + 61440);
  float* cnh    = (float*)(ws + 65536);         // 4KB
  float* psum   = (float*)(ws + 73728);         // 8KB (2048 f32)
  float* psq    = (float*)(ws + 81920);         // 8KB
  int*   ids    = (int*)(ws + 131072);          // 512KB
  const size_t MB = 1u << 20;
  unsigned short* wh2 = (unsigned short*)(ws + MB);
  unsigned short* wm2 = (unsigned short*)(ws + MB + 524288u);
  unsigned short* wl2 = (unsigned short*)(ws + MB + 1048576u);
  unsigned short* wh3 = (unsigned short*)(ws + MB + 1572864u);
  unsigned short* wm3 = (unsigned short*)(ws + MB + 2097152u);
  unsigned short* wl3 = (unsigned short*)(ws + MB + 2621440u);
  unsigned short* wh4 = (unsigned short*)(ws + MB + 3145728u);
  unsigned short* wm4 = (unsigned short*)(ws + MB + 3670016u);
  unsigned short* wl4 = (unsigned short*)(ws + MB + 4194304u);

  float* half1 = (float*)d_out;                 // ends as z_e (B,T,E) f32
  float* half2 = half1 + (size_t)33554432;      // ends as z_q (B,T,E) f32
  unsigned short* cbh = (unsigned short*)half2;             // 512KB (post-conv4)
  unsigned short* cbl = (unsigned short*)half2 + 262144;    // 512KB

  prep_w_kernel<<<1024, 256, 0, stream>>>(w2, wh2, wm2, wl2);
  prep_w_kernel<<<1024, 256, 0, stream>>>(w3, wh3, wm3, wl3);
  prep_w_kernel<<<1024, 256, 0, stream>>>(w4, wh4, wm4, wl4);

  // h1 -> half2 (+tail)
  conv1_kernel<<<dim3(17, 32), 256, 0, stream>>>(x, w1, b1, half2, tailA);
  bn_pass1<<<2048, 256, 0, stream>>>(half2, tailA, psum, psq);
  bn_pass2<<<1, 256, 0, stream>>>(psum, psq, g1, be1, scale1, shift1, 1);
  // h2 -> half1
  conv_mfma<0><<<dim3(32, 2, 32), 256, 0, stream>>>(half2, tailA, wh2, wm2, wl2, b2,
                                                    scale1, shift1, half1, nullptr, 1);
  bn_pass1<<<2048, 256, 0, stream>>>(half1, nullptr, psum, psq);
  bn_pass2<<<1, 256, 0, stream>>>(psum, psq, g2, be2, scale2, shift2, 0);
  // h3 -> half2 (+tail), h1 dead
  conv_mfma<1><<<dim3(33, 2, 32), 256, 0, stream>>>(half1, nullptr, wh3, wm3, wl3, b3,
                                                    scale2, shift2, half2, tailA, 2);
  bn_pass1<<<2048, 256, 0, stream>>>(half2, tailA, psum, psq);
  bn_pass2<<<1, 256, 0, stream>>>(psum, psq, g3, be3, scale3, shift3, 1);
  // z -> half1 (= z_e), h2 dead
  conv_mfma<2><<<dim3(32, 2, 32), 256, 0, stream>>>(half2, tailA, wh4, wm4, wl4, b4,
                                                    scale3, shift3, half1, nullptr, 1);
  // h3 dead: split codebook into half2, VQ, gather overwrites
  cbprep_kernel<<<256, 256, 0, stream>>>(cb, cbh, cbl, cnh);
  vq_mfma_kernel<<<1024, 256, 0, stream>>>(half1, cbh, cbl, cnh, ids);
  gather_kernel<<<32768, 256, 0, stream>>>(ids, cb, half2);
}

// Round 13
// 1459.984 us; speedup vs baseline: 9.0139x; 1.0015x over previous
//
#include <hip/hip_runtime.h>
#include <hip/hip_bf16.h>

// VQ-VAE encoder, round 13: r12 (proven, 1462us) with conv_mfma inner loop
// restructured into latency-ordered plane passes (P1 AhBh, P2 AhBm, P3 AmBh,
// P4 AhBl, P5 AmBm, P6 AlBh) + kt unroll. Same math, same operands, same
// staging — only instruction order. Everything else r12 verbatim.

#define B_   32
#define T_   4096
#define E_   256
#define CIN_ 12
#define LM_  4096

typedef __attribute__((ext_vector_type(4))) float f32x4;
typedef __attribute__((ext_vector_type(8))) short bf16x8;
typedef __attribute__((ext_vector_type(8))) unsigned short u16x8;

__device__ __forceinline__ unsigned int bf_rne(float v) {
  unsigned int u = __float_as_uint(v);
  return (u + 0x7fffu + ((u >> 16) & 1u)) >> 16;
}
__device__ __forceinline__ void split2(float v, unsigned short& h, unsigned short& l) {
  unsigned int hu = bf_rne(v);
  h = (unsigned short)hu;
  l = (unsigned short)bf_rne(v - __uint_as_float(hu << 16));
}
__device__ __forceinline__ void split3(float v, unsigned short& a,
                                       unsigned short& b, unsigned short& c) {
  unsigned int h = bf_rne(v);
  a = (unsigned short)h;
  float r1 = v - __uint_as_float(h << 16);
  unsigned int m = bf_rne(r1);
  b = (unsigned short)m;
  float r2 = r1 - __uint_as_float(m << 16);
  c = (unsigned short)bf_rne(r2);
}

// ---- prep_w (r12 verbatim) ----
__global__ __launch_bounds__(256) void prep_w_kernel(
    const float* __restrict__ w, unsigned short* __restrict__ wh,
    unsigned short* __restrict__ wm, unsigned short* __restrict__ wl) {
  const int g = blockIdx.x * 256 + threadIdx.x;
  const int coff  = g & 31;
  const int e     = (g >> 5) & 255;
  const int slice = g >> 13;
  const int cc = slice >> 2, kt = slice & 3;
  const int c = cc * 32 + coff;
  unsigned short h, m, l;
  split3(w[(size_t)e * 1024 + (size_t)c * 4 + kt], h, m, l);
  const size_t o = (size_t)slice * 8192 + (size_t)e * 32 + coff;
  wh[o] = h; wm[o] = m; wl[o] = l;
}

// ---- conv1 (r12 verbatim) ----
__global__ __launch_bounds__(256) void conv1_kernel(
    const float* __restrict__ x, const float* __restrict__ w1,
    const float* __restrict__ b1, float* __restrict__ out_main,
    float* __restrict__ out_tail) {
  __shared__ __align__(16) float xs[259][12];
  __shared__ __align__(16) float wsh[E_ * 48];
  __shared__ float bs[E_];
  const int tid = threadIdx.x;
  const int b = blockIdx.y;
  const int l0 = blockIdx.x * 256;
  for (int idx = tid; idx < 259 * 12; idx += 256) {
    int r = idx / 12, c = idx - r * 12;
    int t = l0 - 2 + r;
    xs[r][c] = (t >= 0 && t < T_) ? x[((size_t)b * T_ + t) * CIN_ + c] : 0.f;
  }
  for (int idx = tid; idx < E_ * 48; idx += 256) wsh[idx] = w1[idx];
  bs[tid] = b1[tid];
  __syncthreads();
  float xr[4][12];
  #pragma unroll
  for (int r = 0; r < 4; ++r)
    #pragma unroll
    for (int c = 0; c < 12; ++c) xr[r][c] = xs[tid + r][c];
  const int l = l0 + tid;
  for (int e = 0; e < E_; ++e) {
    float acc = bs[e];
    #pragma unroll
    for (int c = 0; c < 12; ++c) {
      const float4 wv = *(const float4*)&wsh[e * 48 + c * 4];
      acc += wv.x * xr[0][c] + wv.y * xr[1][c] + wv.z * xr[2][c] + wv.w * xr[3][c];
    }
    if (l < LM_)       out_main[((size_t)b * E_ + e) * LM_ + l] = acc;
    else if (l == LM_) out_tail[(size_t)b * E_ + e] = acc;
  }
}

// ---- BN stats two-pass (r12 verbatim) ----
__global__ __launch_bounds__(256) void bn_pass1(
    const float* __restrict__ hmain, const float* __restrict__ htail,
    float* __restrict__ psum, float* __restrict__ psq) {
  const int bx = blockIdx.x;
  const int c = bx >> 3, sl = bx & 7;
  const int tid = threadIdx.x;
  float s = 0.f, s2 = 0.f;
  for (int b = 0; b < B_; ++b) {
    const float* p = hmain + ((size_t)b * E_ + c) * LM_ + sl * 512;
    const float v0 = p[tid], v1 = p[tid + 256];
    s += v0 + v1;
    s2 += v0 * v0 + v1 * v1;
  }
  if (htail && sl == 7 && tid < B_) {
    const float v = htail[(size_t)tid * E_ + c];
    s += v; s2 += v * v;
  }
  __shared__ float sh[256], sh2[256];
  sh[tid] = s; sh2[tid] = s2; __syncthreads();
  for (int off = 128; off > 0; off >>= 1) {
    if (tid < off) { sh[tid] += sh[tid + off]; sh2[tid] += sh2[tid + off]; }
    __syncthreads();
  }
  if (tid == 0) { psum[bx] = sh[0]; psq[bx] = sh2[0]; }
}

__global__ __launch_bounds__(256) void bn_pass2(
    const float* __restrict__ psum, const float* __restrict__ psq,
    const float* __restrict__ g, const float* __restrict__ be,
    float* __restrict__ scale, float* __restrict__ shift, int hasTail) {
  const int c = threadIdx.x;
  double s = 0.0, s2 = 0.0;
  #pragma unroll
  for (int i = 0; i < 8; ++i) { s += psum[c * 8 + i]; s2 += psq[c * 8 + i]; }
  double N = (double)B_ * (double)(LM_ + hasTail);
  double m = s / N, var = s2 / N - m * m;
  double a = (double)g[c] / sqrt(var + 1e-5);
  scale[c] = (float)a;
  shift[c] = (float)((double)be[c] - m * a);
}

// ---- MFMA conv: r12 staging/epilogue, latency-ordered MFMA passes ----
template <int MODE>
__global__ __launch_bounds__(256) void conv_mfma(
    const float* __restrict__ in_main, const float* __restrict__ in_tail,
    const unsigned short* __restrict__ wh, const unsigned short* __restrict__ wm,
    const unsigned short* __restrict__ wl, const float* __restrict__ bias,
    const float* __restrict__ scale, const float* __restrict__ shift,
    float* __restrict__ out, float* __restrict__ out_tail, int pad) {
  __shared__ __align__(16) char XhB[132 * 64];
  __shared__ __align__(16) char XmB[132 * 64];
  __shared__ __align__(16) char XlB[132 * 64];
  __shared__ float sc_sh[E_], sf_sh[E_];
  const int tid = threadIdx.x, lane = tid & 63, wv = tid >> 6;
  const int q = lane >> 4, n16 = lane & 15;
  const int b = blockIdx.z, e0 = blockIdx.y * 128, l0 = blockIdx.x * 128;
  const int eB = e0 + (wv & 1) * 64;
  const int lB = (wv >> 1) * 64;
  sc_sh[tid] = scale[tid]; sf_sh[tid] = shift[tid];

  f32x4 acc[4][4];
  #pragma unroll
  for (int i = 0; i < 4; ++i)
    #pragma unroll
    for (int j = 0; j < 4; ++j) acc[i][j] = (f32x4){0.f, 0.f, 0.f, 0.f};

  const float* inb = in_main + (size_t)b * E_ * LM_;
  const float* intb = in_tail ? (in_tail + (size_t)b * E_) : nullptr;

  for (int cc = 0; cc < 8; ++cc) {
    __syncthreads();
    for (int idx = tid; idx < 528; idx += 256) {
      const int cp = idx & 15, uq = idx >> 4;
      const int c = cc * 32 + cp * 2;
      const int u0 = uq * 4;
      const int lb = l0 - pad + u0;
      const float* pa = inb + (size_t)c * LM_;
      const float* pb = pa + LM_;
      const float sca = sc_sh[c], sfa = sf_sh[c];
      const float scb = sc_sh[c + 1], sfb = sf_sh[c + 1];
      float fa[4], fb[4];
      if (lb >= 0 && lb + 3 < LM_) {
        const f32x4 va = *(const f32x4*)(pa + lb);
        const f32x4 vb = *(const f32x4*)(pb + lb);
        #pragma unroll
        for (int s = 0; s < 4; ++s) {
          fa[s] = fmaxf(fmaf(va[s], sca, sfa), 0.f);
          fb[s] = fmaxf(fmaf(vb[s], scb, sfb), 0.f);
        }
      } else {
        #pragma unroll
        for (int s = 0; s < 4; ++s) {
          const int l = lb + s;
          float oa = 0.f, ob = 0.f;
          if (l >= 0 && l < LM_) {
            oa = fmaxf(fmaf(pa[l], sca, sfa), 0.f);
            ob = fmaxf(fmaf(pb[l], scb, sfb), 0.f);
          } else if (l == LM_ && intb) {
            oa = fmaxf(fmaf(intb[c], sca, sfa), 0.f);
            ob = fmaxf(fmaf(intb[c + 1], scb, sfb), 0.f);
          }
          fa[s] = oa; fb[s] = ob;
        }
      }
      const int cg = cp >> 2;
      const int cb4 = (cp & 3) * 4;
      #pragma unroll
      for (int s = 0; s < 4; ++s) {
        const int u = u0 + s;
        unsigned short ha, ma, la, hb, mb, lb2;
        split3(fa[s], ha, ma, la);
        split3(fb[s], hb, mb, lb2);
        const int off = u * 64 + ((cg ^ ((u >> 1) & 3)) << 4) + cb4;
        *(unsigned int*)(XhB + off) = (unsigned int)ha | ((unsigned int)hb << 16);
        *(unsigned int*)(XmB + off) = (unsigned int)ma | ((unsigned int)mb << 16);
        *(unsigned int*)(XlB + off) = (unsigned int)la | ((unsigned int)lb2 << 16);
      }
    }
    __syncthreads();
    #pragma unroll
    for (int kt = 0; kt < 4; ++kt) {
      // issue order: Bh, Ah (needed by P1) .. Bm (P2) .. Am (P3) .. Bl (P4) .. Al (P6)
      bf16x8 Bh[4], Bm[4], Bl[4];
      int xoff[4];
      #pragma unroll
      for (int ni = 0; ni < 4; ++ni) {
        const int u = lB + ni * 16 + n16 + kt;
        xoff[ni] = u * 64 + ((q ^ ((u >> 1) & 3)) << 4);
        Bh[ni] = *(const bf16x8*)(XhB + xoff[ni]);
      }
      const size_t so = (size_t)(cc * 4 + kt) * 8192 + (size_t)q * 8;
      size_t ao[4];
      bf16x8 Ah[4], Am[4], Al[4];
      #pragma unroll
      for (int mi = 0; mi < 4; ++mi) {
        ao[mi] = so + (size_t)(eB + mi * 16 + n16) * 32;
        Ah[mi] = *(const bf16x8*)(wh + ao[mi]);
      }
      #pragma unroll
      for (int ni = 0; ni < 4; ++ni) Bm[ni] = *(const bf16x8*)(XmB + xoff[ni]);
      #pragma unroll
      for (int mi = 0; mi < 4; ++mi) Am[mi] = *(const bf16x8*)(wm + ao[mi]);
      #pragma unroll
      for (int ni = 0; ni < 4; ++ni) Bl[ni] = *(const bf16x8*)(XlB + xoff[ni]);
      #pragma unroll
      for (int mi = 0; mi < 4; ++mi) Al[mi] = *(const bf16x8*)(wl + ao[mi]);

      // P1: Ah*Bh
      #pragma unroll
      for (int mi = 0; mi < 4; ++mi)
        #pragma unroll
        for (int ni = 0; ni < 4; ++ni)
          acc[mi][ni] = __builtin_amdgcn_mfma_f32_16x16x32_bf16(Ah[mi], Bh[ni], acc[mi][ni], 0, 0, 0);
      // P2: Ah*Bm
      #pragma unroll
      for (int mi = 0; mi < 4; ++mi)
        #pragma unroll
        for (int ni = 0; ni < 4; ++ni)
          acc[mi][ni] = __builtin_amdgcn_mfma_f32_16x16x32_bf16(Ah[mi], Bm[ni], acc[mi][ni], 0, 0, 0);
      // P3: Am*Bh
      #pragma unroll
      for (int mi = 0; mi < 4; ++mi)
        #pragma unroll
        for (int ni = 0; ni < 4; ++ni)
          acc[mi][ni] = __builtin_amdgcn_mfma_f32_16x16x32_bf16(Am[mi], Bh[ni], acc[mi][ni], 0, 0, 0);
      // P4: Ah*Bl
      #pragma unroll
      for (int mi = 0; mi < 4; ++mi)
        #pragma unroll
        for (int ni = 0; ni < 4; ++ni)
          acc[mi][ni] = __builtin_amdgcn_mfma_f32_16x16x32_bf16(Ah[mi], Bl[ni], acc[mi][ni], 0, 0, 0);
      // P5: Am*Bm
      #pragma unroll
      for (int mi = 0; mi < 4; ++mi)
        #pragma unroll
        for (int ni = 0; ni < 4; ++ni)
          acc[mi][ni] = __builtin_amdgcn_mfma_f32_16x16x32_bf16(Am[mi], Bm[ni], acc[mi][ni], 0, 0, 0);
      // P6: Al*Bh
      #pragma unroll
      for (int mi = 0; mi < 4; ++mi)
        #pragma unroll
        for (int ni = 0; ni < 4; ++ni)
          acc[mi][ni] = __builtin_amdgcn_mfma_f32_16x16x32_bf16(Al[mi], Bh[ni], acc[mi][ni], 0, 0, 0);
    }
  }

  #pragma unroll
  for (int mi = 0; mi < 4; ++mi) {
    const int eb4 = eB + mi * 16 + q * 4;
    const f32x4 bv = *(const f32x4*)(bias + eb4);
    #pragma unroll
    for (int ni = 0; ni < 4; ++ni) {
      const int col = l0 + lB + ni * 16 + n16;
      const f32x4 r = acc[mi][ni] + bv;
      if constexpr (MODE == 0) {
        #pragma unroll
        for (int rr = 0; rr < 4; ++rr)
          out[((size_t)b * E_ + eb4 + rr) * LM_ + col] = r[rr];
      } else if constexpr (MODE == 1) {
        if (col < LM_) {
          #pragma unroll
          for (int rr = 0; rr < 4; ++rr)
            out[((size_t)b * E_ + eb4 + rr) * LM_ + col] = r[rr];
        } else if (col == LM_) {
          #pragma unroll
          for (int rr = 0; rr < 4; ++rr)
            out_tail[(size_t)b * E_ + eb4 + rr] = r[rr];
        }
      } else {
        #pragma unroll
        for (int rr = 0; rr < 4; ++rr)
          out[((size_t)b * T_ + col) * E_ + eb4 + rr] = r[rr];
      }
    }
  }
}

// ---- cbprep (r12 verbatim) ----
__global__ __launch_bounds__(256) void cbprep_kernel(
    const float* __restrict__ cb, unsigned short* __restrict__ cbh,
    unsigned short* __restrict__ cbl, float* __restrict__ cnh) {
  const int code = blockIdx.x * 4 + (threadIdx.x >> 6);
  const int lane = threadIdx.x & 63;
  const f32x4 v = *(const f32x4*)&cb[(size_t)code * E_ + lane * 4];
  ushort4 h, l;
  split2(v.x, h.x, l.x); split2(v.y, h.y, l.y);
  split2(v.z, h.z, l.z); split2(v.w, h.w, l.w);
  *(ushort4*)&cbh[(size_t)code * E_ + lane * 4] = h;
  *(ushort4*)&cbl[(size_t)code * E_ + lane * 4] = l;
  float s = v.x * v.x + v.y * v.y + v.z * v.z + v.w * v.w;
  for (int off = 32; off > 0; off >>= 1) s += __shfl_xor(s, off, 64);
  if (lane == 0) cnh[code] = 0.5f * s;
}

// ---- MFMA VQ (r12 verbatim: LDS-staged, double-buffered) ----
__global__ __launch_bounds__(256) void vq_mfma_kernel(
    const float* __restrict__ z, const unsigned short* __restrict__ cbh,
    const unsigned short* __restrict__ cbl, const float* __restrict__ cnh,
    int* __restrict__ ids) {
  __shared__ __align__(16) char cbLds[2][16384];
  __shared__ float cn_sh[1024];
  const int tid = threadIdx.x;
  const int lane = tid & 63;
  const int w = tid >> 6;
  const int q = lane >> 4;
  const int m15 = lane & 15;
  const int rbase = blockIdx.x * 128 + w * 32;
  for (int i = tid; i < 1024; i += 256) cn_sh[i] = cnh[i];

  const int sc0 = tid >> 5, sl0 = tid & 31;
  const int sc1 = (tid + 256) >> 5, sl1 = (tid + 256) & 31;
  const int d0 = sc0 * 512 + (((sl0 ^ (sc0 & 7))) << 4);
  const int d1 = sc1 * 512 + (((sl1 ^ (sc1 & 7))) << 4);
  const u16x8* srcH = (const u16x8*)cbh;
  const u16x8* srcL = (const u16x8*)cbl;

  {
    u16x8 h0 = srcH[tid], h1 = srcH[tid + 256];
    u16x8 l0 = srcL[tid], l1 = srcL[tid + 256];
    *(u16x8*)(cbLds[0] + d0) = h0;
    *(u16x8*)(cbLds[0] + d1) = h1;
    *(u16x8*)(cbLds[0] + 8192 + d0) = l0;
    *(u16x8*)(cbLds[0] + 8192 + d1) = l1;
  }

  bf16x8 zh[2][8], zl[2][8];
  #pragma unroll
  for (int g = 0; g < 2; ++g) {
    const int row = rbase + g * 16 + m15;
    const float* zr = z + (size_t)row * 256 + q * 8;
    #pragma unroll
    for (int ec = 0; ec < 8; ++ec) {
      const f32x4 v0 = *(const f32x4*)(zr + ec * 32);
      const f32x4 v1 = *(const f32x4*)(zr + ec * 32 + 4);
      u16x8 h, l;
      #pragma unroll
      for (int j = 0; j < 4; ++j) {
        unsigned short a, b;
        split2(v0[j], a, b); h[j] = a; l[j] = b;
        split2(v1[j], a, b); h[4 + j] = a; l[4 + j] = b;
      }
      zh[g][ec] = (bf16x8)h;
      zl[g][ec] = (bf16x8)l;
    }
  }
  __syncthreads();

  float best[2] = {-3.4e38f, -3.4e38f};
  int bidx[2] = {0, 0};
  const int swz = (m15 & 7) << 4;
  const int rowOff = m15 * 512;

  for (int cg = 0; cg < 64; ++cg) {
    const int cur = cg & 1;
    u16x8 ph0, ph1, pl0, pl1;
    if (cg < 63) {
      const int sb = (cg + 1) * 512;
      ph0 = srcH[sb + tid]; ph1 = srcH[sb + tid + 256];
      pl0 = srcL[sb + tid]; pl1 = srcL[sb + tid + 256];
    }
    const char* baseH = cbLds[cur];
    const char* baseL = cbLds[cur] + 8192;
    f32x4 ahh[2], ahl[2], alh[2];
    #pragma unroll
    for (int g = 0; g < 2; ++g) {
      ahh[g] = (f32x4){0.f, 0.f, 0.f, 0.f};
      ahl[g] = (f32x4){0.f, 0.f, 0.f, 0.f};
      alh[g] = (f32x4){0.f, 0.f, 0.f, 0.f};
    }
    #pragma unroll
    for (int ec = 0; ec < 8; ++ec) {
      const int co = rowOff + ((q * 16 + ec * 64) ^ swz);
      const bf16x8 Ah = *(const bf16x8*)(baseH + co);
      const bf16x8 Al = *(const bf16x8*)(baseL + co);
      #pragma unroll
      for (int g = 0; g < 2; ++g) {
        ahh[g] = __builtin_amdgcn_mfma_f32_16x16x32_bf16(Ah, zh[g][ec], ahh[g], 0, 0, 0);
        ahl[g] = __builtin_amdgcn_mfma_f32_16x16x32_bf16(Ah, zl[g][ec], ahl[g], 0, 0, 0);
        alh[g] = __builtin_amdgcn_mfma_f32_16x16x32_bf16(Al, zh[g][ec], alh[g], 0, 0, 0);
      }
    }
    const f32x4 cn = *(const f32x4*)&cn_sh[cg * 16 + q * 4];
    #pragma unroll
    for (int g = 0; g < 2; ++g) {
      #pragma unroll
      for (int r = 0; r < 4; ++r) {
        const float s = (ahh[g][r] + ahl[g][r]) + alh[g][r] - cn[r];
        const int code = cg * 16 + q * 4 + r;
        if (s > best[g]) { best[g] = s; bidx[g] = code; }
      }
    }
    if (cg < 63) {
      char* nb = cbLds[cur ^ 1];
      *(u16x8*)(nb + d0) = ph0;
      *(u16x8*)(nb + d1) = ph1;
      *(u16x8*)(nb + 8192 + d0) = pl0;
      *(u16x8*)(nb + 8192 + d1) = pl1;
    }
    __syncthreads();
  }

  #pragma unroll
  for (int g = 0; g < 2; ++g) {
    #pragma unroll
    for (int off = 16; off <= 32; off <<= 1) {
      const float ov = __shfl_xor(best[g], off, 64);
      const int oi = __shfl_xor(bidx[g], off, 64);
      if (ov > best[g] || (ov == best[g] && oi < bidx[g])) { best[g] = ov; bidx[g] = oi; }
    }
  }
  if (q == 0) {
    #pragma unroll
    for (int g = 0; g < 2; ++g) ids[rbase + g * 16 + lane] = bidx[g];
  }
}

// ---- gather (r12 verbatim) ----
__global__ __launch_bounds__(256) void gather_kernel(
    const int* __restrict__ ids, const float* __restrict__ cb,
    float* __restrict__ zq) {
  const int row = blockIdx.x * 4 + (threadIdx.x >> 6);
  const int lane = threadIdx.x & 63;
  const int id = ids[row];
  const float4 v = *(const float4*)&cb[(size_t)id * E_ + lane * 4];
  *(float4*)&zq[(size_t)row * E_ + lane * 4] = v;
}

extern "C" void kernel_launch(void* const* d_in, const int* in_sizes, int n_in,
                              void* d_out, int out_size, void* d_ws, size_t ws_size,
                              hipStream_t stream) {
  const float* x   = (const float*)d_in[0];
  const float* w1  = (const float*)d_in[1];
  const float* b1  = (const float*)d_in[2];
  const float* g1  = (const float*)d_in[3];
  const float* be1 = (const float*)d_in[4];
  const float* w2  = (const float*)d_in[5];
  const float* b2  = (const float*)d_in[6];
  const float* g2  = (const float*)d_in[7];
  const float* be2 = (const float*)d_in[8];
  const float* w3  = (const float*)d_in[9];
  const float* b3  = (const float*)d_in[10];
  const float* g3  = (const float*)d_in[11];
  const float* be3 = (const float*)d_in[12];
  const float* w4  = (const float*)d_in[13];
  const float* b4  = (const float*)d_in[14];
  const float* cb  = (const float*)d_in[15];

  char* ws = (char*)d_ws;
  float* tailA  = (float*)(ws);
  float* scale1 = (float*)(ws + 40960);  float* shift1 = (float*)(ws + 45056);
  float* scale2 = (float*)(ws + 49152);  float* shift2 = (float*)(ws + 53248);
  float* scale3 = (float*)(ws + 57344);  float* shift3 = (float*)(ws + 61440);
  float* cnh    = (float*)(ws + 65536);
  float* psum   = (float*)(ws + 73728);
  float* psq    = (float*)(ws + 81920);
  int*   ids    = (int*)(ws + 131072);
  const size_t MB = 1u << 20;
  unsigned short* wh2 = (unsigned short*)(ws + MB);
  unsigned short* wm2 = (unsigned short*)(ws + MB + 524288u);
  unsigned short* wl2 = (unsigned short*)(ws + MB + 1048576u);
  unsigned short* wh3 = (unsigned short*)(ws + MB + 1572864u);
  unsigned short* wm3 = (unsigned short*)(ws + MB + 2097152u);
  unsigned short* wl3 = (unsigned short*)(ws + MB + 2621440u);
  unsigned short* wh4 = (unsigned short*)(ws + MB + 3145728u);
  unsigned short* wm4 = (unsigned short*)(ws + MB + 3670016u);
  unsigned short* wl4 = (unsigned short*)(ws + MB + 4194304u);

  float* half1 = (float*)d_out;
  float* half2 = half1 + (size_t)33554432;
  unsigned short* cbh = (unsigned short*)half2;
  unsigned short* cbl = (unsigned short*)half2 + 262144;

  prep_w_kernel<<<1024, 256, 0, stream>>>(w2, wh2, wm2, wl2);
  prep_w_kernel<<<1024, 256, 0, stream>>>(w3, wh3, wm3, wl3);
  prep_w_kernel<<<1024, 256, 0, stream>>>(w4, wh4, wm4, wl4);

  conv1_kernel<<<dim3(17, 32), 256, 0, stream>>>(x, w1, b1, half2, tailA);
  bn_pass1<<<2048, 256, 0, stream>>>(half2, tailA, psum, psq);
  bn_pass2<<<1, 256, 0, stream>>>(psum, psq, g1, be1, scale1, shift1, 1);
  conv_mfma<0><<<dim3(32, 2, 32), 256, 0, stream>>>(half2, tailA, wh2, wm2, wl2, b2,
                                                    scale1, shift1, half1, nullptr, 1);
  bn_pass1<<<2048, 256, 0, stream>>>(half1, nullptr, psum, psq);
  bn_pass2<<<1, 256, 0, stream>>>(psum, psq, g2, be2, scale2, shift2, 0);
  conv_mfma<1><<<dim3(33, 2, 32), 256, 0, stream>>>(half1, nullptr, wh3, wm3, wl3, b3,
                                                    scale2, shift2, half2, tailA, 2);
  bn_pass1<<<2048, 256, 0, stream>>>(half2, tailA, psum, psq);
  bn_pass2<<<1, 256, 0, stream>>>(psum, psq, g3, be3, scale3, shift3, 1);
  conv_mfma<2><<<dim3(32, 2, 32), 256, 0, stream>>>(half2, tailA, wh4, wm4, wl4, b4,
                                                    scale3, shift3, half1, nullptr, 1);
  cbprep_kernel<<<256, 256, 0, stream>>>(cb, cbh, cbl, cnh);
  vq_mfma_kernel<<<1024, 256, 0, stream>>>(half1, cbh, cbl, cnh, ids);
  gather_kernel<<<32768, 256, 0, stream>>>(ids, cb, half2);
}